// Round 7
// baseline (362.032 us; speedup 1.0000x reference)
//
#include <hip/hip_runtime.h>
#include <hip/hip_bf16.h>
#include <math.h>

#define HH 48
#define WW 48
#define HW 2304
#define BB 4
#define CC 256

typedef __hip_bfloat16 bf16;
typedef __attribute__((ext_vector_type(8))) short s8v;
typedef __attribute__((ext_vector_type(4))) float f4v;

__device__ inline float bf2f(short u) {
  unsigned v = ((unsigned)(unsigned short)u) << 16;
  return __builtin_bit_cast(float, v);
}

// ---------------- LDS tile transpose: fmap [B][C][HW] fp32 -> [B*HW][256] bf16 ----
__global__ __launch_bounds__(256) void transp_bf_k(const float* __restrict__ in,
                                                   bf16* __restrict__ out) {
  __shared__ float t[64][65];
  int p0 = blockIdx.x * 64, c0 = blockIdx.y * 64, b = blockIdx.z;
  const float* inb = in + ((size_t)b * CC + c0) * HW + p0;
#pragma unroll
  for (int i = 0; i < 16; ++i) {
    int idx = threadIdx.x + i * 256;
    int c = idx >> 6, p = idx & 63;
    t[c][p] = inb[(size_t)c * HW + p];
  }
  __syncthreads();
  bf16* ob = out + ((size_t)b * HW + p0) * 256 + c0;
#pragma unroll
  for (int i = 0; i < 16; ++i) {
    int idx = threadIdx.x + i * 256;
    int p = idx >> 6, c = idx & 63;
    ob[(size_t)p * 256 + c] = (bf16)t[c][p];
  }
}

// ---------------- fmap1 transpose + srcT fp32 + f1T bf16 + q=(src+pos) bf16 ----
__global__ __launch_bounds__(256) void pos_q_tile_k(const float* __restrict__ fmap1,
                                                    float* __restrict__ srcT,
                                                    bf16* __restrict__ f1t,
                                                    bf16* __restrict__ qb) {
  __shared__ float t[64][65];
  int p0 = blockIdx.x * 64, c0 = blockIdx.y * 64, b = blockIdx.z;
  const float* inb = fmap1 + ((size_t)b * CC + c0) * HW + p0;
#pragma unroll
  for (int i = 0; i < 16; ++i) {
    int idx = threadIdx.x + i * 256;
    int c = idx >> 6, p = idx & 63;
    t[c][p] = inb[(size_t)c * HW + p];
  }
  __syncthreads();
  const float TWO_PI = 6.283185307179586f;
#pragma unroll
  for (int i = 0; i < 16; ++i) {
    int idx = threadIdx.x + i * 256;
    int pl = idx >> 6, cl = idx & 63;
    int c = c0 + cl;
    int p = p0 + pl;
    int y = p / WW, x = p % WW;
    float s = t[cl][pl];
    int axis = c >> 7;
    int cc = c & 127;
    int m = cc >> 1;
    float coord = (axis ? ((float)x + 0.5f) : ((float)y + 0.5f)) * (TWO_PI / (48.f + 1e-6f));
    float tp = exp2f((float)m * (13.287712379549449f / 64.f));
    float a = coord / tp;
    float pv = (cc & 1) ? cosf(a) : sinf(a);
    size_t o = ((size_t)b * HW + p) * 256 + c;
    srcT[o] = s;
    f1t[o] = (bf16)s;
    qb[o] = (bf16)(s + pv);
  }
}

// ======== shared 128x64-tile GEMM body pieces (KC=64 per stage, slot^=(row&7)) ========
// LDS: As[128][64] shorts (16KB), Bs[64][64] shorts (8KB).
// A-staging: thread owns row tid>>1, base slot (tid&1)*4, 4 x 16B stores.
// B-staging: thread owns row tid>>2, base slot (tid&3)*2, 2 x 16B stores.
// Waves: wm=(wave>>1)*64, wn=(wave&1)*32; fragments af[4], bf[2]; acc[4][2].

// ---------------- corr MFMA: corr[b][q][k] = (f1t[q].f2t[k])/16, bf16 out ----
__global__ __launch_bounds__(256) void corr_mfma_k(const bf16* __restrict__ f1t,
                                                   const bf16* __restrict__ f2t,
                                                   bf16* __restrict__ corr) {
  int b = blockIdx.z;
  int m0 = blockIdx.y * 128, n0 = blockIdx.x * 64;
  __shared__ short As[128][64];
  __shared__ short Bs[64][64];
  int tid = threadIdx.x;
  int arl = tid >> 1, asl = (tid & 1) * 4;
  int brl = tid >> 2, bsl = (tid & 3) * 2;
  int wave = tid >> 6, lane = tid & 63;
  int wm = (wave >> 1) * 64, wn = (wave & 1) * 32;
  int fl = lane & 15, fk8 = lane >> 4;
  f4v acc[4][2] = {};
  const bf16* arow = f1t + ((size_t)b * HW + m0 + arl) * 256;
  const bf16* brow = f2t + ((size_t)b * HW + n0 + brl) * 256;
#pragma unroll
  for (int c0 = 0; c0 < 256; c0 += 64) {
#pragma unroll
    for (int q = 0; q < 4; ++q) {
      int sr = asl + q;
      *(uint4*)&As[arl][((sr ^ (arl & 7))) * 8] = *(const uint4*)(arow + c0 + sr * 8);
    }
#pragma unroll
    for (int q = 0; q < 2; ++q) {
      int sr = bsl + q;
      *(uint4*)&Bs[brl][((sr ^ (brl & 7))) * 8] = *(const uint4*)(brow + c0 + sr * 8);
    }
    __syncthreads();
#pragma unroll
    for (int cc = 0; cc < 2; ++cc) {
      s8v af[4], bfr[2];
#pragma unroll
      for (int i = 0; i < 4; ++i) {
        int ar = wm + i * 16 + fl;
        af[i] = *(const s8v*)&As[ar][(((cc * 4 + fk8) ^ (ar & 7))) * 8];
      }
#pragma unroll
      for (int j = 0; j < 2; ++j) {
        int br = wn + j * 16 + fl;
        bfr[j] = *(const s8v*)&Bs[br][(((cc * 4 + fk8) ^ (br & 7))) * 8];
      }
#pragma unroll
      for (int i = 0; i < 4; ++i)
#pragma unroll
        for (int j = 0; j < 2; ++j)
          acc[i][j] = __builtin_amdgcn_mfma_f32_16x16x32_bf16(af[i], bfr[j], acc[i][j], 0, 0, 0);
    }
    __syncthreads();
  }
  bf16* outp = corr + ((size_t)b * HW + m0) * HW + n0;
#pragma unroll
  for (int j = 0; j < 2; ++j) {
    int o = wn + j * 16 + fl;
#pragma unroll
    for (int i = 0; i < 4; ++i)
#pragma unroll
      for (int r = 0; r < 4; ++r) {
        int m = wm + i * 16 + fk8 * 4 + r;
        outp[(size_t)m * HW + o] = (bf16)(acc[i][j][r] * 0.0625f);
      }
  }
}

// ---------------- 81-tap bilinear correlation lookup (bf16 corr) -> [n][96] bf16 ----
__global__ __launch_bounds__(256) void corr_lookup_k(const bf16* __restrict__ corr,
                                                     const float* __restrict__ flow,
                                                     bf16* __restrict__ cf) {
  int g = blockIdx.x * 256 + threadIdx.x;  // n*96 + t
  int t = g % 96;
  int n = g / 96;
  if (t >= 81) { cf[g] = (bf16)0.f; return; }
  int b = n / HW;
  int p = n % HW;
  int y = p / WW, x = p % WW;
  float fx = flow[((size_t)b * 2 + 0) * HW + p];
  float fy = flow[((size_t)b * 2 + 1) * HW + p];
  float px = (float)x + fx + (float)(t / 9 - 4);
  float py = (float)y + fy + (float)(t % 9 - 4);
  const bf16* row = corr + (size_t)n * HW;
  float x0f = floorf(px), y0f = floorf(py);
  int x0 = (int)x0f, y0 = (int)y0f;
  float wx = px - x0f, wy = py - y0f;
  float acc = 0.f;
  if ((unsigned)x0 < WW && (unsigned)y0 < HH) acc += (float)row[y0 * WW + x0] * (1.f - wx) * (1.f - wy);
  if ((unsigned)(x0 + 1) < WW && (unsigned)y0 < HH) acc += (float)row[y0 * WW + x0 + 1] * wx * (1.f - wy);
  if ((unsigned)x0 < WW && (unsigned)(y0 + 1) < HH) acc += (float)row[(y0 + 1) * WW + x0] * (1.f - wx) * wy;
  if ((unsigned)(x0 + 1) < WW && (unsigned)(y0 + 1) < HH) acc += (float)row[(y0 + 1) * WW + x0 + 1] * wx * wy;
  cf[g] = (bf16)acc;
}

// ---------------- fused weight conversion: 12 segments (KS2==0 => conv7 repack) ----
struct WtSegs {
  const float* src[12];
  unsigned dstOff[12];
  int Cout[12], Cin[12], KP[12], KS2[12];
  unsigned cum[13];
};

__global__ __launch_bounds__(256) void wt_all_k(WtSegs s, bf16* __restrict__ base) {
  unsigned idx = blockIdx.x * 256 + threadIdx.x;
  if (idx >= s.cum[12]) return;
  int seg = 0;
#pragma unroll
  for (int i = 1; i < 12; ++i)
    if (idx >= s.cum[i]) seg = i;
  unsigned r = idx - s.cum[seg];
  int KP = s.KP[seg], Cout = s.Cout[seg], Cin = s.Cin[seg], KS2 = s.KS2[seg];
  int c = r % KP;
  int o = (r / KP) % Cout;
  int t = r / (KP * Cout);
  float v;
  if (KS2 == 0) {
    int cc = c >> 6, tt = c & 63;
    v = (tt < 49) ? s.src[seg][((size_t)o * 2 + cc) * 49 + tt] : 0.f;
  } else {
    v = (c < Cin) ? s.src[seg][((size_t)o * Cin + c) * KS2 + t] : 0.f;
  }
  base[s.dstOff[seg] + r] = (bf16)v;
}

// ---------------- im2col for 7x7 pad3 conv on flow: col7[n][128] bf16 ----
__global__ __launch_bounds__(256) void im2col7_k(const float* __restrict__ flow,
                                                 bf16* __restrict__ col7) {
  int g = blockIdx.x * 256 + threadIdx.x;  // n*128 + kp
  int kp = g & 127;
  int n = g >> 7;
  int b = n / HW;
  int p = n % HW;
  int y = p / WW, x = p % WW;
  int cc = kp >> 6, tt = kp & 63;
  float v = 0.f;
  if (tt < 49) {
    int ky = tt / 7, kx = tt % 7;
    int yy = y + ky - 3, xx = x + kx - 3;
    if ((unsigned)yy < (unsigned)HH && (unsigned)xx < (unsigned)WW)
      v = flow[((size_t)b * 2 + cc) * HW + yy * WW + xx];
  }
  col7[g] = (bf16)v;
}

// ---------------- implicit-GEMM MFMA conv, 128x64 tile, batch folded into M ----
template <int TAPS, int KP>
__global__ __launch_bounds__(256) void conv_mfma_k(const bf16* __restrict__ in,
                                                   const bf16* __restrict__ wt,
                                                   const float* __restrict__ bias,
                                                   bf16* __restrict__ out, int Cout,
                                                   int OStride, int OOff, int relu) {
  int m0 = blockIdx.y * 128;  // global row in [0, B*HW)
  int n0 = blockIdx.x * 64;
  __shared__ short As[128][64];
  __shared__ short Bs[64][64];
  int tid = threadIdx.x;
  int arl = tid >> 1, asl = (tid & 1) * 4;
  int brl = tid >> 2, bsl = (tid & 3) * 2;
  int wave = tid >> 6, lane = tid & 63;
  int wm = (wave >> 1) * 64, wn = (wave & 1) * 32;
  int fl = lane & 15, fk8 = lane >> 4;
  f4v acc[4][2] = {};
  int m = m0 + arl;
  int b = m / HW;
  int p = m - b * HW;
  int y = p / WW, x = p - y * WW;
  int wo = n0 + brl;
  bool wvalid = wo < Cout;
  int wo_c = wvalid ? wo : 0;
  for (int t = 0; t < TAPS; ++t) {
    int ky = (TAPS == 9) ? t / 3 : 0;
    int kx = (TAPS == 9) ? t - ky * 3 : 0;
    int yy = (TAPS == 9) ? (y + ky - 1) : y;
    int xx = (TAPS == 9) ? (x + kx - 1) : x;
    bool valid = ((unsigned)yy < (unsigned)HH) & ((unsigned)xx < (unsigned)WW);
    const bf16* arow = in + ((size_t)b * HW + yy * WW + xx) * KP;
    const bf16* wrow = wt + ((size_t)t * Cout + wo_c) * KP;
#pragma unroll
    for (int c0 = 0; c0 < KP; c0 += 64) {
#pragma unroll
      for (int q = 0; q < 4; ++q) {
        int sr = asl + q;
        uint4 av = {0u, 0u, 0u, 0u};
        if (valid && (c0 + sr * 8) < KP) av = *(const uint4*)(arow + c0 + sr * 8);
        *(uint4*)&As[arl][((sr ^ (arl & 7))) * 8] = av;
      }
#pragma unroll
      for (int q = 0; q < 2; ++q) {
        int sr = bsl + q;
        uint4 bv = {0u, 0u, 0u, 0u};
        if (wvalid && (c0 + sr * 8) < KP) bv = *(const uint4*)(wrow + c0 + sr * 8);
        *(uint4*)&Bs[brl][((sr ^ (brl & 7))) * 8] = bv;
      }
      __syncthreads();
#pragma unroll
      for (int cc = 0; cc < 2; ++cc) {
        s8v af[4], bfr[2];
#pragma unroll
        for (int i = 0; i < 4; ++i) {
          int ar = wm + i * 16 + fl;
          af[i] = *(const s8v*)&As[ar][(((cc * 4 + fk8) ^ (ar & 7))) * 8];
        }
#pragma unroll
        for (int j = 0; j < 2; ++j) {
          int br = wn + j * 16 + fl;
          bfr[j] = *(const s8v*)&Bs[br][(((cc * 4 + fk8) ^ (br & 7))) * 8];
        }
#pragma unroll
        for (int i = 0; i < 4; ++i)
#pragma unroll
          for (int j = 0; j < 2; ++j)
            acc[i][j] = __builtin_amdgcn_mfma_f32_16x16x32_bf16(af[i], bfr[j], acc[i][j], 0, 0, 0);
      }
      __syncthreads();
    }
  }
#pragma unroll
  for (int j = 0; j < 2; ++j) {
    int o = n0 + wn + j * 16 + fl;
    if (o < Cout) {
      float bsv = bias[o];
#pragma unroll
      for (int i = 0; i < 4; ++i)
#pragma unroll
        for (int r = 0; r < 4; ++r) {
          int mm = m0 + wm + i * 16 + fk8 * 4 + r;
          float v = acc[i][j][r] + bsv;
          if (relu) v = fmaxf(v, 0.f);
          out[(size_t)mm * OStride + OOff + o] = (bf16)v;
        }
    }
  }
}

// ---------------- MFMA linear, 128x64 tile: in [N][KP] bf16, wt [O][KP] bf16 ----
template <int KP, int RELU, int OUTB>
__global__ __launch_bounds__(256) void lin_mfma_k(const bf16* __restrict__ in,
                                                  const bf16* __restrict__ wt,
                                                  const float* __restrict__ bias,
                                                  const float* __restrict__ bias2,
                                                  int split,
                                                  float* __restrict__ outf,
                                                  bf16* __restrict__ outb, int O) {
  int m0 = blockIdx.y * 128;
  int n0 = blockIdx.x * 64;
  __shared__ short As[128][64];
  __shared__ short Bs[64][64];
  int tid = threadIdx.x;
  int arl = tid >> 1, asl = (tid & 1) * 4;
  int brl = tid >> 2, bsl = (tid & 3) * 2;
  int wave = tid >> 6, lane = tid & 63;
  int wm = (wave >> 1) * 64, wn = (wave & 1) * 32;
  int fl = lane & 15, fk8 = lane >> 4;
  f4v acc[4][2] = {};
  const bf16* arow = in + (size_t)(m0 + arl) * KP;
  int wo = n0 + brl;
  bool wvalid = wo < O;
  const bf16* wrow = wt + (size_t)(wvalid ? wo : 0) * KP;
  for (int c0 = 0; c0 < KP; c0 += 64) {
#pragma unroll
    for (int q = 0; q < 4; ++q) {
      int sr = asl + q;
      *(uint4*)&As[arl][((sr ^ (arl & 7))) * 8] = *(const uint4*)(arow + c0 + sr * 8);
    }
#pragma unroll
    for (int q = 0; q < 2; ++q) {
      int sr = bsl + q;
      uint4 bv = {0u, 0u, 0u, 0u};
      if (wvalid) bv = *(const uint4*)(wrow + c0 + sr * 8);
      *(uint4*)&Bs[brl][((sr ^ (brl & 7))) * 8] = bv;
    }
    __syncthreads();
#pragma unroll
    for (int cc = 0; cc < 2; ++cc) {
      s8v af[4], bfr[2];
#pragma unroll
      for (int i = 0; i < 4; ++i) {
        int ar = wm + i * 16 + fl;
        af[i] = *(const s8v*)&As[ar][(((cc * 4 + fk8) ^ (ar & 7))) * 8];
      }
#pragma unroll
      for (int j = 0; j < 2; ++j) {
        int br = wn + j * 16 + fl;
        bfr[j] = *(const s8v*)&Bs[br][(((cc * 4 + fk8) ^ (br & 7))) * 8];
      }
#pragma unroll
      for (int i = 0; i < 4; ++i)
#pragma unroll
        for (int j = 0; j < 2; ++j)
          acc[i][j] = __builtin_amdgcn_mfma_f32_16x16x32_bf16(af[i], bfr[j], acc[i][j], 0, 0, 0);
    }
    __syncthreads();
  }
#pragma unroll
  for (int j = 0; j < 2; ++j) {
    int o = n0 + wn + j * 16 + fl;
    if (o < O) {
      float bsv = (bias2 != nullptr && o >= split) ? bias2[o - split] : bias[o];
#pragma unroll
      for (int i = 0; i < 4; ++i)
#pragma unroll
        for (int r = 0; r < 4; ++r) {
          int mm = m0 + wm + i * 16 + fk8 * 4 + r;
          float v = acc[i][j][r] + bsv;
          if (RELU) v = fmaxf(v, 0.f);
          if (OUTB) outb[(size_t)mm * O + o] = (bf16)v;
          else outf[(size_t)mm * O + o] = v;
        }
    }
  }
}

// ---------------- final 3x3 conv 256->2, wave-per-pixel, LDS weights ----------------
__global__ __launch_bounds__(256) void convfh2_k(const bf16* __restrict__ fh1,
                                                 const float* __restrict__ w,
                                                 const float* __restrict__ bias,
                                                 float* __restrict__ out) {
  __shared__ float wl[4608];
  int tid = threadIdx.x;
#pragma unroll
  for (int i = tid; i < 4608; i += 256) {
    int o2 = i & 1;
    int t = (i >> 1) % 9;
    int c = i / 18;
    wl[i] = w[((size_t)o2 * 256 + c) * 9 + t];
  }
  __syncthreads();
  int wave = tid >> 6, lane = tid & 63;
  int pix = blockIdx.x * 4 + wave;
  int b = pix / HW;
  int q = pix % HW;
  int y = q / WW, x = q % WW;
  int c0 = lane * 4;
  float a0 = 0.f, a1 = 0.f;
#pragma unroll
  for (int ky = 0; ky < 3; ++ky) {
    int yy = y + ky - 1;
    if ((unsigned)yy >= (unsigned)HH) continue;
#pragma unroll
    for (int kx = 0; kx < 3; ++kx) {
      int xx = x + kx - 1;
      if ((unsigned)xx >= (unsigned)WW) continue;
      int t = ky * 3 + kx;
      const bf16* row = fh1 + ((size_t)b * HW + yy * WW + xx) * 256 + c0;
      ushort4 v = *(const ushort4*)row;
      unsigned short vv[4] = {v.x, v.y, v.z, v.w};
#pragma unroll
      for (int j = 0; j < 4; ++j) {
        float fv = bf2f((short)vv[j]);
        float2 wp = *(const float2*)&wl[((c0 + j) * 9 + t) * 2];
        a0 += fv * wp.x;
        a1 += fv * wp.y;
      }
    }
  }
#pragma unroll
  for (int offl = 32; offl > 0; offl >>= 1) {
    a0 += __shfl_xor(a0, offl);
    a1 += __shfl_xor(a1, offl);
  }
  if (lane == 0) {
    out[(size_t)b * 2 * HW + q] = a0 + bias[0];
    out[((size_t)b * 2 + 1) * HW + q] = a1 + bias[1];
  }
}

// ---------------- copy flow into mf cols 126,127 ----------------
__global__ void copy_flow_k(const float* __restrict__ flow, bf16* __restrict__ mf) {
  int g = blockIdx.x * 256 + threadIdx.x;
  int p = g % HW;
  int c = (g / HW) % 2;
  int b = g / (2 * HW);
  mf[((size_t)b * HW + p) * 128 + 126 + c] = (bf16)flow[g];
}

// ---------------- deformable sampling with inline softmax; oa=[n][96] (off|aw) ----
__global__ __launch_bounds__(256) void deform_k(const float* __restrict__ val,
                                                const float* __restrict__ oa,
                                                bf16* __restrict__ attn) {
  int g = blockIdx.x * 256 + threadIdx.x;
  int d = g & 31;
  int nh = g >> 5;
  int h = nh & 7;
  int n = nh >> 3;
  int b = n / HW;
  int p = n % HW;
  int y = p / WW, x = p % WW;
  const float* ap = oa + (size_t)n * 96 + 64 + h * 4;
  float l0 = ap[0], l1 = ap[1], l2 = ap[2], l3 = ap[3];
  float mx = fmaxf(fmaxf(l0, l1), fmaxf(l2, l3));
  float e0 = expf(l0 - mx), e1 = expf(l1 - mx), e2 = expf(l2 - mx), e3 = expf(l3 - mx);
  float inv = 1.f / (e0 + e1 + e2 + e3);
  float wts[4] = {e0 * inv, e1 * inv, e2 * inv, e3 * inv};
  const float* offp = oa + (size_t)n * 96 + h * 8;
  const float* vb = val + (size_t)b * HW * 256 + h * 32 + d;
  float acc = 0.f;
#pragma unroll
  for (int pt = 0; pt < 4; ++pt) {
    float ox = offp[pt * 2 + 0];
    float oy = offp[pt * 2 + 1];
    float w = wts[pt];
    float px = (float)x + ox, py = (float)y + oy;
    float x0f = floorf(px), y0f = floorf(py);
    int x0 = (int)x0f, y0 = (int)y0f;
    float wx = px - x0f, wy = py - y0f;
    float s = 0.f;
    if ((unsigned)x0 < WW && (unsigned)y0 < HH)
      s += vb[(size_t)(y0 * WW + x0) * 256] * (1.f - wx) * (1.f - wy);
    if ((unsigned)(x0 + 1) < WW && (unsigned)y0 < HH)
      s += vb[(size_t)(y0 * WW + x0 + 1) * 256] * wx * (1.f - wy);
    if ((unsigned)x0 < WW && (unsigned)(y0 + 1) < HH)
      s += vb[(size_t)((y0 + 1) * WW + x0) * 256] * (1.f - wx) * wy;
    if ((unsigned)(x0 + 1) < WW && (unsigned)(y0 + 1) < HH)
      s += vb[(size_t)((y0 + 1) * WW + x0 + 1) * 256] * wx * wy;
    acc += w * s;
  }
  attn[(size_t)n * 256 + h * 32 + d] = (bf16)acc;
}

// ---------------- fused residual add + LayerNorm over 256 (optional bf16 copy) ----
__global__ __launch_bounds__(256) void ln_add_k(const float* __restrict__ A,
                                                const float* __restrict__ Bv,
                                                const float* __restrict__ g,
                                                const float* __restrict__ be,
                                                float* __restrict__ out,
                                                bf16* __restrict__ outb) {
  int n = blockIdx.x;
  int c = threadIdx.x;
  float v = A[(size_t)n * 256 + c] + Bv[(size_t)n * 256 + c];
  float s1 = v, s2 = v * v;
#pragma unroll
  for (int o = 32; o > 0; o >>= 1) {
    s1 += __shfl_down(s1, o);
    s2 += __shfl_down(s2, o);
  }
  __shared__ float r1[4], r2[4], mv[2];
  int wid = c >> 6, lane = c & 63;
  if (lane == 0) {
    r1[wid] = s1;
    r2[wid] = s2;
  }
  __syncthreads();
  if (c == 0) {
    float a = r1[0] + r1[1] + r1[2] + r1[3];
    float q2 = r2[0] + r2[1] + r2[2] + r2[3];
    float mean = a * (1.f / 256.f);
    mv[0] = mean;
    mv[1] = q2 * (1.f / 256.f) - mean * mean;
  }
  __syncthreads();
  float mean = mv[0], var = mv[1];
  float r = (v - mean) * rsqrtf(var + 1e-5f) * g[c] + be[c];
  out[(size_t)n * 256 + c] = r;
  if (outb) outb[(size_t)n * 256 + c] = (bf16)r;
}

extern "C" void kernel_launch(void* const* d_in, const int* in_sizes, int n_in,
                              void* d_out, int out_size, void* d_ws, size_t ws_size,
                              hipStream_t stream) {
  const float* fmap1 = (const float*)d_in[0];
  const float* fmap2 = (const float*)d_in[1];
  const float* flow = (const float*)d_in[2];
  const float* wc1 = (const float*)d_in[3];
  const float* bc1 = (const float*)d_in[4];
  const float* wc2 = (const float*)d_in[5];
  const float* bc2 = (const float*)d_in[6];
  const float* wf1 = (const float*)d_in[7];
  const float* bf1 = (const float*)d_in[8];
  const float* wf2 = (const float*)d_in[9];
  const float* bf2 = (const float*)d_in[10];
  const float* wcf = (const float*)d_in[11];
  const float* bcf = (const float*)d_in[12];
  const float* wfh1 = (const float*)d_in[13];
  const float* bfh1 = (const float*)d_in[14];
  const float* wfh2 = (const float*)d_in[15];
  const float* bfh2 = (const float*)d_in[16];
  const float* w_off = (const float*)d_in[17];
  const float* b_off = (const float*)d_in[18];
  const float* w_aw = (const float*)d_in[19];
  const float* b_aw = (const float*)d_in[20];
  const float* w_val = (const float*)d_in[21];
  const float* b_val = (const float*)d_in[22];
  const float* w_out = (const float*)d_in[23];
  const float* b_out = (const float*)d_in[24];
  const float* ln1_g = (const float*)d_in[25];
  const float* ln1_b = (const float*)d_in[26];
  const float* w_ff1 = (const float*)d_in[27];
  const float* b_ff1 = (const float*)d_in[28];
  const float* w_ff2 = (const float*)d_in[29];
  const float* b_ff2 = (const float*)d_in[30];
  const float* ln2_g = (const float*)d_in[31];
  const float* ln2_b = (const float*)d_in[32];

  float* ws = (float*)d_ws;
  float* out_src = (float*)d_out;
  float* out_df = out_src + (size_t)BB * HW * CC;

  // ---- workspace layout (float offsets), same as round 6 ----
  const size_t F_CORR = 0;
  const size_t F_F1T = 10616832;
  const size_t F_F2T = 11796480;
  const size_t F_CF = 12976128;
  const size_t F_SRCT = 13418496;
  const size_t F_QBF = 15777792;
  const size_t F_WK = 0;
  const size_t F_COL7 = 950000;
  const size_t F_COR1 = 1600000;
  const size_t F_CAT = 2800000;
  const size_t F_FLO1 = 4000000;
  const size_t F_MF = 4600000;
  const size_t F_FH1 = 5200000;
  const size_t F_OA = 5200000;
  const size_t F_VAL = 6100000;
  const size_t F_ATTN = 8500000;
  const size_t F_TMP = 10616832;
  const size_t F_SRC1 = 15777792;
  const size_t F_SRC1B = 18137088;
  const size_t F_FF1 = 1000000;
  const size_t F_FF2 = 5800000;

  bf16* corrb = (bf16*)(ws + F_CORR);
  bf16* f1t = (bf16*)(ws + F_F1T);
  bf16* f2t = (bf16*)(ws + F_F2T);
  bf16* cf = (bf16*)(ws + F_CF);
  bf16* qb = (bf16*)(ws + F_QBF);
  bf16* wkbase = (bf16*)(ws + F_WK);
  bf16* wk1 = wkbase + 0;
  bf16* wk2 = wkbase + 24576;
  bf16* wkf2 = wkbase + 466944;
  bf16* wkcf = wkbase + 540672;
  bf16* wkfh1 = wkbase + 830976;
  bf16* wl_oa = wkbase + 1125888;
  bf16* wl_val = wkbase + 1150464;
  bf16* wl_out = wkbase + 1216000;
  bf16* wl_ff1 = wkbase + 1281536;
  bf16* wl_ff2 = wkbase + 1543680;
  bf16* wk7 = wkbase + 1805824;
  bf16* col7 = (bf16*)(ws + F_COL7);
  bf16* cor1 = (bf16*)(ws + F_COR1);
  bf16* cat = (bf16*)(ws + F_CAT);
  bf16* flo1 = (bf16*)(ws + F_FLO1);
  bf16* mf = (bf16*)(ws + F_MF);
  bf16* fh1 = (bf16*)(ws + F_FH1);
  bf16* attnb = (bf16*)(ws + F_ATTN);
  bf16* src1b = (bf16*)(ws + F_SRC1B);
  bf16* ff1b = (bf16*)(ws + F_FF1);

  // Phase A: transposes + corr + lookup
  transp_bf_k<<<dim3(36, 4, 4), 256, 0, stream>>>(fmap2, f2t);
  pos_q_tile_k<<<dim3(36, 4, 4), 256, 0, stream>>>(fmap1, ws + F_SRCT, f1t, qb);
  corr_mfma_k<<<dim3(36, 18, 4), 256, 0, stream>>>(f1t, f2t, corrb);
  corr_lookup_k<<<dim3(3456), 256, 0, stream>>>(corrb, flow, cf);

  // fused weight conversion (corr region dead now)
  WtSegs segs;
  const float* srcs[12] = {wc1, wc2, wf2, wcf, wfh1, w_off, w_aw, w_val, w_out, w_ff1, w_ff2, wf1};
  unsigned offs[12] = {0, 24576, 466944, 540672, 830976, 1125888, 1142272, 1150464, 1216000, 1281536, 1543680, 1805824};
  int couts[12] = {256, 192, 64, 126, 256, 64, 32, 256, 256, 1024, 256, 128};
  int cins[12] = {81, 256, 128, 256, 128, 256, 256, 256, 256, 256, 1024, 2};
  int kps[12] = {96, 256, 128, 256, 128, 256, 256, 256, 256, 256, 1024, 128};
  int ks2[12] = {1, 9, 9, 9, 9, 1, 1, 1, 1, 1, 1, 0};
  unsigned cum = 0;
  for (int i = 0; i < 12; ++i) {
    segs.src[i] = srcs[i];
    segs.dstOff[i] = offs[i];
    segs.Cout[i] = couts[i];
    segs.Cin[i] = cins[i];
    segs.KP[i] = kps[i];
    segs.KS2[i] = ks2[i];
    segs.cum[i] = cum;
    cum += (unsigned)((ks2[i] ? ks2[i] : 1) * couts[i] * kps[i]);
  }
  segs.cum[12] = cum;
  wt_all_k<<<dim3((cum + 255) / 256), 256, 0, stream>>>(segs, wkbase);

  // motion encoder + flow head (batch folded into M: 9216/128 = 72 M-blocks)
  conv_mfma_k<1, 96><<<dim3(4, 72), 256, 0, stream>>>(cf, wk1, bc1, cor1, 256, 256, 0, 1);
  conv_mfma_k<9, 256><<<dim3(3, 72), 256, 0, stream>>>(cor1, wk2, bc2, cat, 192, 256, 0, 1);
  im2col7_k<<<dim3(4608), 256, 0, stream>>>(flow, col7);
  lin_mfma_k<128, 1, 1><<<dim3(2, 72), 256, 0, stream>>>(col7, wk7, bf1, nullptr, 1 << 30, nullptr, flo1, 128);
  conv_mfma_k<9, 128><<<dim3(1, 72), 256, 0, stream>>>(flo1, wkf2, bf2, cat, 64, 256, 192, 1);
  conv_mfma_k<9, 256><<<dim3(2, 72), 256, 0, stream>>>(cat, wkcf, bcf, mf, 126, 128, 0, 1);
  copy_flow_k<<<dim3(72), 256, 0, stream>>>(flow, mf);
  conv_mfma_k<9, 128><<<dim3(4, 72), 256, 0, stream>>>(mf, wkfh1, bfh1, fh1, 256, 256, 0, 1);
  convfh2_k<<<dim3(2304), 256, 0, stream>>>(fh1, wfh2, bfh2, out_df);

  // attention path
  lin_mfma_k<256, 0, 0><<<dim3(2, 72), 256, 0, stream>>>(qb, wl_oa, b_off, b_aw, 64, ws + F_OA, nullptr, 96);
  lin_mfma_k<256, 0, 0><<<dim3(4, 72), 256, 0, stream>>>(f1t, wl_val, b_val, nullptr, 1 << 30, ws + F_VAL, nullptr, 256);
  deform_k<<<dim3(9216), 256, 0, stream>>>(ws + F_VAL, ws + F_OA, attnb);
  lin_mfma_k<256, 0, 0><<<dim3(4, 72), 256, 0, stream>>>(attnb, wl_out, b_out, nullptr, 1 << 30, ws + F_TMP, nullptr, 256);
  ln_add_k<<<dim3(9216), 256, 0, stream>>>(ws + F_TMP, ws + F_SRCT, ln1_g, ln1_b, ws + F_SRC1, src1b);
  lin_mfma_k<256, 1, 1><<<dim3(16, 72), 256, 0, stream>>>(src1b, wl_ff1, b_ff1, nullptr, 1 << 30, nullptr, ff1b, 1024);
  lin_mfma_k<1024, 0, 0><<<dim3(4, 72), 256, 0, stream>>>(ff1b, wl_ff2, b_ff2, nullptr, 1 << 30, ws + F_FF2, nullptr, 256);
  ln_add_k<<<dim3(9216), 256, 0, stream>>>(ws + F_FF2, ws + F_SRC1, ln2_g, ln2_b, out_src, nullptr);

  (void)in_sizes; (void)n_in; (void)out_size; (void)ws_size;
}

// Round 8
// 300.305 us; speedup vs baseline: 1.2055x; 1.2055x over previous
//
#include <hip/hip_runtime.h>
#include <hip/hip_bf16.h>
#include <math.h>

#define HH 48
#define WW 48
#define HW 2304
#define BB 4
#define CC 256

typedef __hip_bfloat16 bf16;
typedef __attribute__((ext_vector_type(8))) short s8v;
typedef __attribute__((ext_vector_type(4))) float f4v;

__device__ inline float bf2f(short u) {
  unsigned v = ((unsigned)(unsigned short)u) << 16;
  return __builtin_bit_cast(float, v);
}

// ---------------- prep: z<4 -> fmap2 transpose; z>=4 -> fmap1 transpose + srcT/qb ----
__global__ __launch_bounds__(256) void prep_k(const float* __restrict__ fmap1,
                                              const float* __restrict__ fmap2,
                                              float* __restrict__ srcT,
                                              bf16* __restrict__ f1t,
                                              bf16* __restrict__ qb,
                                              bf16* __restrict__ f2t) {
  __shared__ float t[64][65];
  int z = blockIdx.z;
  int p0 = blockIdx.x * 64, c0 = blockIdx.y * 64;
  int b = z & 3;
  const float* src = (z < 4) ? fmap2 : fmap1;
  const float* inb = src + ((size_t)b * CC + c0) * HW + p0;
#pragma unroll
  for (int i = 0; i < 16; ++i) {
    int idx = threadIdx.x + i * 256;
    int c = idx >> 6, p = idx & 63;
    t[c][p] = inb[(size_t)c * HW + p];
  }
  __syncthreads();
  if (z < 4) {
    bf16* ob = f2t + ((size_t)b * HW + p0) * 256 + c0;
#pragma unroll
    for (int i = 0; i < 16; ++i) {
      int idx = threadIdx.x + i * 256;
      int p = idx >> 6, c = idx & 63;
      ob[(size_t)p * 256 + c] = (bf16)t[c][p];
    }
  } else {
    const float TWO_PI = 6.283185307179586f;
#pragma unroll
    for (int i = 0; i < 16; ++i) {
      int idx = threadIdx.x + i * 256;
      int pl = idx >> 6, cl = idx & 63;
      int c = c0 + cl;
      int p = p0 + pl;
      int y = p / WW, x = p % WW;
      float s = t[cl][pl];
      int axis = c >> 7;
      int cc = c & 127;
      int mm = cc >> 1;
      float coord = (axis ? ((float)x + 0.5f) : ((float)y + 0.5f)) * (TWO_PI / (48.f + 1e-6f));
      float tp = exp2f((float)mm * (13.287712379549449f / 64.f));
      float a = coord / tp;
      float pv = (cc & 1) ? cosf(a) : sinf(a);
      size_t o = ((size_t)b * HW + p) * 256 + c;
      srcT[o] = s;
      f1t[o] = (bf16)s;
      qb[o] = (bf16)(s + pv);
    }
  }
}

// ---------------- corr MFMA 128x64: corr[b][q][k] = (f1t[q].f2t[k])/16 ----
__global__ __launch_bounds__(256) void corr_mfma_k(const bf16* __restrict__ f1t,
                                                   const bf16* __restrict__ f2t,
                                                   bf16* __restrict__ corr) {
  int b = blockIdx.z;
  int m0 = blockIdx.y * 128, n0 = blockIdx.x * 64;
  __shared__ short As[128][64];
  __shared__ short Bs[64][64];
  int tid = threadIdx.x;
  int arl = tid >> 1, asl = (tid & 1) * 4;
  int brl = tid >> 2, bsl = (tid & 3) * 2;
  int wave = tid >> 6, lane = tid & 63;
  int wm = (wave >> 1) * 64, wn = (wave & 1) * 32;
  int fl = lane & 15, fk8 = lane >> 4;
  f4v acc[4][2] = {};
  const bf16* arow = f1t + ((size_t)b * HW + m0 + arl) * 256;
  const bf16* brow = f2t + ((size_t)b * HW + n0 + brl) * 256;
#pragma unroll
  for (int c0 = 0; c0 < 256; c0 += 64) {
#pragma unroll
    for (int q = 0; q < 4; ++q) {
      int sr = asl + q;
      *(uint4*)&As[arl][((sr ^ (arl & 7))) * 8] = *(const uint4*)(arow + c0 + sr * 8);
    }
#pragma unroll
    for (int q = 0; q < 2; ++q) {
      int sr = bsl + q;
      *(uint4*)&Bs[brl][((sr ^ (brl & 7))) * 8] = *(const uint4*)(brow + c0 + sr * 8);
    }
    __syncthreads();
#pragma unroll
    for (int cc = 0; cc < 2; ++cc) {
      s8v af[4], bfr[2];
#pragma unroll
      for (int i = 0; i < 4; ++i) {
        int ar = wm + i * 16 + fl;
        af[i] = *(const s8v*)&As[ar][(((cc * 4 + fk8) ^ (ar & 7))) * 8];
      }
#pragma unroll
      for (int j = 0; j < 2; ++j) {
        int br = wn + j * 16 + fl;
        bfr[j] = *(const s8v*)&Bs[br][(((cc * 4 + fk8) ^ (br & 7))) * 8];
      }
#pragma unroll
      for (int i = 0; i < 4; ++i)
#pragma unroll
        for (int j = 0; j < 2; ++j)
          acc[i][j] = __builtin_amdgcn_mfma_f32_16x16x32_bf16(af[i], bfr[j], acc[i][j], 0, 0, 0);
    }
    __syncthreads();
  }
  bf16* outp = corr + ((size_t)b * HW + m0) * HW + n0;
#pragma unroll
  for (int j = 0; j < 2; ++j) {
    int o = wn + j * 16 + fl;
#pragma unroll
    for (int i = 0; i < 4; ++i)
#pragma unroll
      for (int r = 0; r < 4; ++r) {
        int m = wm + i * 16 + fk8 * 4 + r;
        outp[(size_t)m * HW + o] = (bf16)(acc[i][j][r] * 0.0625f);
      }
  }
}

// ---------------- 81-tap bilinear correlation lookup -> [n][96] bf16 ----
__global__ __launch_bounds__(256) void corr_lookup_k(const bf16* __restrict__ corr,
                                                     const float* __restrict__ flow,
                                                     bf16* __restrict__ cf) {
  int g = blockIdx.x * 256 + threadIdx.x;  // n*96 + t
  int t = g % 96;
  int n = g / 96;
  if (t >= 81) { cf[g] = (bf16)0.f; return; }
  int b = n / HW;
  int p = n % HW;
  int y = p / WW, x = p % WW;
  float fx = flow[((size_t)b * 2 + 0) * HW + p];
  float fy = flow[((size_t)b * 2 + 1) * HW + p];
  float px = (float)x + fx + (float)(t / 9 - 4);
  float py = (float)y + fy + (float)(t % 9 - 4);
  const bf16* row = corr + (size_t)n * HW;
  float x0f = floorf(px), y0f = floorf(py);
  int x0 = (int)x0f, y0 = (int)y0f;
  float wx = px - x0f, wy = py - y0f;
  float acc = 0.f;
  if ((unsigned)x0 < WW && (unsigned)y0 < HH) acc += (float)row[y0 * WW + x0] * (1.f - wx) * (1.f - wy);
  if ((unsigned)(x0 + 1) < WW && (unsigned)y0 < HH) acc += (float)row[y0 * WW + x0 + 1] * wx * (1.f - wy);
  if ((unsigned)x0 < WW && (unsigned)(y0 + 1) < HH) acc += (float)row[(y0 + 1) * WW + x0] * (1.f - wx) * wy;
  if ((unsigned)(x0 + 1) < WW && (unsigned)(y0 + 1) < HH) acc += (float)row[(y0 + 1) * WW + x0 + 1] * wx * wy;
  cf[g] = (bf16)acc;
}

// ---------------- fused weight conversion: 12 segments (KS2==0 => conv7 repack) ----
struct WtSegs {
  const float* src[12];
  unsigned dstOff[12];
  int Cout[12], Cin[12], KP[12], KS2[12];
  unsigned cum[13];
};

__global__ __launch_bounds__(256) void wt_all_k(WtSegs s, bf16* __restrict__ base) {
  unsigned idx = blockIdx.x * 256 + threadIdx.x;
  if (idx >= s.cum[12]) return;
  int seg = 0;
#pragma unroll
  for (int i = 1; i < 12; ++i)
    if (idx >= s.cum[i]) seg = i;
  unsigned r = idx - s.cum[seg];
  int KP = s.KP[seg], Cout = s.Cout[seg], Cin = s.Cin[seg], KS2 = s.KS2[seg];
  int c = r % KP;
  int o = (r / KP) % Cout;
  int t = r / (KP * Cout);
  float v;
  if (KS2 == 0) {
    int cc = c >> 6, tt = c & 63;
    v = (tt < 49) ? s.src[seg][((size_t)o * 2 + cc) * 49 + tt] : 0.f;
  } else {
    v = (c < Cin) ? s.src[seg][((size_t)o * Cin + c) * KS2 + t] : 0.f;
  }
  base[s.dstOff[seg] + r] = (bf16)v;
}

// ---------------- im2col for 7x7 pad3 conv on flow: col7[n][128] bf16 ----
__global__ __launch_bounds__(256) void im2col7_k(const float* __restrict__ flow,
                                                 bf16* __restrict__ col7) {
  int g = blockIdx.x * 256 + threadIdx.x;
  int kp = g & 127;
  int n = g >> 7;
  int b = n / HW;
  int p = n % HW;
  int y = p / WW, x = p % WW;
  int cc = kp >> 6, tt = kp & 63;
  float v = 0.f;
  if (tt < 49) {
    int ky = tt / 7, kx = tt % 7;
    int yy = y + ky - 3, xx = x + kx - 3;
    if ((unsigned)yy < (unsigned)HH && (unsigned)xx < (unsigned)WW)
      v = flow[((size_t)b * 2 + cc) * HW + yy * WW + xx];
  }
  col7[g] = (bf16)v;
}

// ---------------- grouped GEMM: up to 4 independent segments per dispatch ----
// 128x64 tile, 4 waves, runtime KP/taps. taps=1 => pure linear (in[m][KP]).
struct GSegs {
  const bf16* in[4];
  const bf16* wt[4];
  const float* bias[4];
  const float* bias2[4];
  float* outf[4];
  bf16* outb[4];
  int split[4], O[4], KP[4], taps[4], OStride[4], OOff[4], relu[4], nTn[4];
  int blkStart[4];
  int nseg;
};

__global__ __launch_bounds__(256) void gemm_group_k(GSegs s) {
  int blk = blockIdx.x;
  int seg = 0;
#pragma unroll
  for (int i = 1; i < 4; ++i)
    if (i < s.nseg && blk >= s.blkStart[i]) seg = i;
  int rel = blk - s.blkStart[seg];
  int nTn = s.nTn[seg];
  int bm = rel / nTn, bn = rel % nTn;
  int m0 = bm * 128, n0 = bn * 64;
  int KP = s.KP[seg], O = s.O[seg], taps = s.taps[seg];
  const bf16* in = s.in[seg];
  const bf16* wt = s.wt[seg];

  __shared__ short As[128][64];
  __shared__ short Bs[64][64];
  int tid = threadIdx.x;
  int arl = tid >> 1, asl = (tid & 1) * 4;
  int brl = tid >> 2, bsl = (tid & 3) * 2;
  int wave = tid >> 6, lane = tid & 63;
  int wm = (wave >> 1) * 64, wn = (wave & 1) * 32;
  int fl = lane & 15, fk8 = lane >> 4;
  f4v acc[4][2] = {};
  int m = m0 + arl;
  int b = m / HW;
  int p = m - b * HW;
  int y = p / WW, x = p - y * WW;
  int wo = n0 + brl;
  bool wvalid = wo < O;
  int wo_c = wvalid ? wo : 0;
  for (int t = 0; t < taps; ++t) {
    int yy = y, xx = x;
    bool valid = true;
    if (taps == 9) {
      int ky = t / 3, kx = t - ky * 3;
      yy = y + ky - 1;
      xx = x + kx - 1;
      valid = ((unsigned)yy < (unsigned)HH) & ((unsigned)xx < (unsigned)WW);
    }
    const bf16* arow = in + ((size_t)b * HW + yy * WW + xx) * KP;
    const bf16* wrow = wt + ((size_t)t * O + wo_c) * KP;
    for (int c0 = 0; c0 < KP; c0 += 64) {
#pragma unroll
      for (int q = 0; q < 4; ++q) {
        int sr = asl + q;
        uint4 av = {0u, 0u, 0u, 0u};
        if (valid && (c0 + sr * 8) < KP) av = *(const uint4*)(arow + c0 + sr * 8);
        *(uint4*)&As[arl][((sr ^ (arl & 7))) * 8] = av;
      }
#pragma unroll
      for (int q = 0; q < 2; ++q) {
        int sr = bsl + q;
        uint4 bv = {0u, 0u, 0u, 0u};
        if (wvalid && (c0 + sr * 8) < KP) bv = *(const uint4*)(wrow + c0 + sr * 8);
        *(uint4*)&Bs[brl][((sr ^ (brl & 7))) * 8] = bv;
      }
      __syncthreads();
#pragma unroll
      for (int cc = 0; cc < 2; ++cc) {
        s8v af[4], bfr[2];
#pragma unroll
        for (int i = 0; i < 4; ++i) {
          int ar = wm + i * 16 + fl;
          af[i] = *(const s8v*)&As[ar][(((cc * 4 + fk8) ^ (ar & 7))) * 8];
        }
#pragma unroll
        for (int j = 0; j < 2; ++j) {
          int br = wn + j * 16 + fl;
          bfr[j] = *(const s8v*)&Bs[br][(((cc * 4 + fk8) ^ (br & 7))) * 8];
        }
#pragma unroll
        for (int i = 0; i < 4; ++i)
#pragma unroll
          for (int j = 0; j < 2; ++j)
            acc[i][j] = __builtin_amdgcn_mfma_f32_16x16x32_bf16(af[i], bfr[j], acc[i][j], 0, 0, 0);
      }
      __syncthreads();
    }
  }
  int OStride = s.OStride[seg], OOff = s.OOff[seg], relu = s.relu[seg], split = s.split[seg];
  const float* bias = s.bias[seg];
  const float* bias2 = s.bias2[seg];
  float* outf = s.outf[seg];
  bf16* outb = s.outb[seg];
#pragma unroll
  for (int j = 0; j < 2; ++j) {
    int o = n0 + wn + j * 16 + fl;
    if (o < O) {
      float bsv = (bias2 != nullptr && o >= split) ? bias2[o - split] : bias[o];
#pragma unroll
      for (int i = 0; i < 4; ++i)
#pragma unroll
        for (int r = 0; r < 4; ++r) {
          int mm = m0 + wm + i * 16 + fk8 * 4 + r;
          float v = acc[i][j][r] + bsv;
          if (relu) v = fmaxf(v, 0.f);
          if (outb) outb[(size_t)mm * OStride + OOff + o] = (bf16)v;
          else outf[(size_t)mm * OStride + OOff + o] = v;
        }
    }
  }
}

// ---------------- final 3x3 conv 256->2, wave-per-pixel, LDS weights ----------------
__global__ __launch_bounds__(256) void convfh2_k(const bf16* __restrict__ fh1,
                                                 const float* __restrict__ w,
                                                 const float* __restrict__ bias,
                                                 float* __restrict__ out) {
  __shared__ float wl[4608];
  int tid = threadIdx.x;
#pragma unroll
  for (int i = tid; i < 4608; i += 256) {
    int o2 = i & 1;
    int t = (i >> 1) % 9;
    int c = i / 18;
    wl[i] = w[((size_t)o2 * 256 + c) * 9 + t];
  }
  __syncthreads();
  int wave = tid >> 6, lane = tid & 63;
  int pix = blockIdx.x * 4 + wave;
  int b = pix / HW;
  int q = pix % HW;
  int y = q / WW, x = q % WW;
  int c0 = lane * 4;
  float a0 = 0.f, a1 = 0.f;
#pragma unroll
  for (int ky = 0; ky < 3; ++ky) {
    int yy = y + ky - 1;
    if ((unsigned)yy >= (unsigned)HH) continue;
#pragma unroll
    for (int kx = 0; kx < 3; ++kx) {
      int xx = x + kx - 1;
      if ((unsigned)xx >= (unsigned)WW) continue;
      int t = ky * 3 + kx;
      const bf16* row = fh1 + ((size_t)b * HW + yy * WW + xx) * 256 + c0;
      ushort4 v = *(const ushort4*)row;
      unsigned short vv[4] = {v.x, v.y, v.z, v.w};
#pragma unroll
      for (int j = 0; j < 4; ++j) {
        float fv = bf2f((short)vv[j]);
        float2 wp = *(const float2*)&wl[((c0 + j) * 9 + t) * 2];
        a0 += fv * wp.x;
        a1 += fv * wp.y;
      }
    }
  }
#pragma unroll
  for (int offl = 32; offl > 0; offl >>= 1) {
    a0 += __shfl_xor(a0, offl);
    a1 += __shfl_xor(a1, offl);
  }
  if (lane == 0) {
    out[(size_t)b * 2 * HW + q] = a0 + bias[0];
    out[((size_t)b * 2 + 1) * HW + q] = a1 + bias[1];
  }
}

// ---------------- copy flow into mf cols 126,127 ----------------
__global__ void copy_flow_k(const float* __restrict__ flow, bf16* __restrict__ mf) {
  int g = blockIdx.x * 256 + threadIdx.x;
  int p = g % HW;
  int c = (g / HW) % 2;
  int b = g / (2 * HW);
  mf[((size_t)b * HW + p) * 128 + 126 + c] = (bf16)flow[g];
}

// ---------------- deformable sampling with inline softmax; oa=[n][96] (off|aw) ----
__global__ __launch_bounds__(256) void deform_k(const float* __restrict__ val,
                                                const float* __restrict__ oa,
                                                bf16* __restrict__ attn) {
  int g = blockIdx.x * 256 + threadIdx.x;
  int d = g & 31;
  int nh = g >> 5;
  int h = nh & 7;
  int n = nh >> 3;
  int b = n / HW;
  int p = n % HW;
  int y = p / WW, x = p % WW;
  const float* ap = oa + (size_t)n * 96 + 64 + h * 4;
  float l0 = ap[0], l1 = ap[1], l2 = ap[2], l3 = ap[3];
  float mx = fmaxf(fmaxf(l0, l1), fmaxf(l2, l3));
  float e0 = expf(l0 - mx), e1 = expf(l1 - mx), e2 = expf(l2 - mx), e3 = expf(l3 - mx);
  float inv = 1.f / (e0 + e1 + e2 + e3);
  float wts[4] = {e0 * inv, e1 * inv, e2 * inv, e3 * inv};
  const float* offp = oa + (size_t)n * 96 + h * 8;
  const float* vb = val + (size_t)b * HW * 256 + h * 32 + d;
  float acc = 0.f;
#pragma unroll
  for (int pt = 0; pt < 4; ++pt) {
    float ox = offp[pt * 2 + 0];
    float oy = offp[pt * 2 + 1];
    float w = wts[pt];
    float px = (float)x + ox, py = (float)y + oy;
    float x0f = floorf(px), y0f = floorf(py);
    int x0 = (int)x0f, y0 = (int)y0f;
    float wx = px - x0f, wy = py - y0f;
    float s = 0.f;
    if ((unsigned)x0 < WW && (unsigned)y0 < HH)
      s += vb[(size_t)(y0 * WW + x0) * 256] * (1.f - wx) * (1.f - wy);
    if ((unsigned)(x0 + 1) < WW && (unsigned)y0 < HH)
      s += vb[(size_t)(y0 * WW + x0 + 1) * 256] * wx * (1.f - wy);
    if ((unsigned)x0 < WW && (unsigned)(y0 + 1) < HH)
      s += vb[(size_t)((y0 + 1) * WW + x0) * 256] * (1.f - wx) * wy;
    if ((unsigned)(x0 + 1) < WW && (unsigned)(y0 + 1) < HH)
      s += vb[(size_t)((y0 + 1) * WW + x0 + 1) * 256] * wx * wy;
    acc += w * s;
  }
  attn[(size_t)n * 256 + h * 32 + d] = (bf16)acc;
}

// ---------------- fused residual add + LayerNorm over 256 (optional bf16 copy) ----
__global__ __launch_bounds__(256) void ln_add_k(const float* __restrict__ A,
                                                const float* __restrict__ Bv,
                                                const float* __restrict__ g,
                                                const float* __restrict__ be,
                                                float* __restrict__ out,
                                                bf16* __restrict__ outb) {
  int n = blockIdx.x;
  int c = threadIdx.x;
  float v = A[(size_t)n * 256 + c] + Bv[(size_t)n * 256 + c];
  float s1 = v, s2 = v * v;
#pragma unroll
  for (int o = 32; o > 0; o >>= 1) {
    s1 += __shfl_down(s1, o);
    s2 += __shfl_down(s2, o);
  }
  __shared__ float r1[4], r2[4], mv[2];
  int wid = c >> 6, lane = c & 63;
  if (lane == 0) {
    r1[wid] = s1;
    r2[wid] = s2;
  }
  __syncthreads();
  if (c == 0) {
    float a = r1[0] + r1[1] + r1[2] + r1[3];
    float q2 = r2[0] + r2[1] + r2[2] + r2[3];
    float mean = a * (1.f / 256.f);
    mv[0] = mean;
    mv[1] = q2 * (1.f / 256.f) - mean * mean;
  }
  __syncthreads();
  float mean = mv[0], var = mv[1];
  float r = (v - mean) * rsqrtf(var + 1e-5f) * g[c] + be[c];
  out[(size_t)n * 256 + c] = r;
  if (outb) outb[(size_t)n * 256 + c] = (bf16)r;
}

extern "C" void kernel_launch(void* const* d_in, const int* in_sizes, int n_in,
                              void* d_out, int out_size, void* d_ws, size_t ws_size,
                              hipStream_t stream) {
  const float* fmap1 = (const float*)d_in[0];
  const float* fmap2 = (const float*)d_in[1];
  const float* flow = (const float*)d_in[2];
  const float* wc1 = (const float*)d_in[3];
  const float* bc1 = (const float*)d_in[4];
  const float* wc2 = (const float*)d_in[5];
  const float* bc2 = (const float*)d_in[6];
  const float* wf1 = (const float*)d_in[7];
  const float* bf1 = (const float*)d_in[8];
  const float* wf2 = (const float*)d_in[9];
  const float* bf2 = (const float*)d_in[10];
  const float* wcf = (const float*)d_in[11];
  const float* bcf = (const float*)d_in[12];
  const float* wfh1 = (const float*)d_in[13];
  const float* bfh1 = (const float*)d_in[14];
  const float* wfh2 = (const float*)d_in[15];
  const float* bfh2 = (const float*)d_in[16];
  const float* w_off = (const float*)d_in[17];
  const float* b_off = (const float*)d_in[18];
  const float* w_aw = (const float*)d_in[19];
  const float* b_aw = (const float*)d_in[20];
  const float* w_val = (const float*)d_in[21];
  const float* b_val = (const float*)d_in[22];
  const float* w_out = (const float*)d_in[23];
  const float* b_out = (const float*)d_in[24];
  const float* ln1_g = (const float*)d_in[25];
  const float* ln1_b = (const float*)d_in[26];
  const float* w_ff1 = (const float*)d_in[27];
  const float* b_ff1 = (const float*)d_in[28];
  const float* w_ff2 = (const float*)d_in[29];
  const float* b_ff2 = (const float*)d_in[30];
  const float* ln2_g = (const float*)d_in[31];
  const float* ln2_b = (const float*)d_in[32];

  float* ws = (float*)d_ws;
  float* out_src = (float*)d_out;
  float* out_df = out_src + (size_t)BB * HW * CC;

  // ---- workspace layout (float offsets), fully de-aliased (~165 MB) ----
  const size_t F_WT = 0;            // bf16 weights, 919,296 fl used
  const size_t F_CORR = 1000000;    // bf16 [B,HW,HW] 10,616,832 fl
  const size_t F_F1T = 11700000;    // bf16 [n][256]
  const size_t F_F2T = 12900000;    // bf16 [n][256]
  const size_t F_QB = 14100000;     // bf16 [n][256]
  const size_t F_SRCT = 15300000;   // fp32 [n][256]
  const size_t F_CF = 17700000;     // bf16 [n][96]
  const size_t F_COL7 = 18200000;   // bf16 [n][128]
  const size_t F_COR1 = 18800000;   // bf16 [n][256]
  const size_t F_FLO1 = 20000000;   // bf16 [n][128]
  const size_t F_CAT = 20600000;    // bf16 [n][256]
  const size_t F_MF = 21800000;     // bf16 [n][128]
  const size_t F_FH1 = 22400000;    // bf16 [n][256]
  const size_t F_OA = 23600000;     // fp32 [n][96]
  const size_t F_VAL = 24500000;    // fp32 [n][256]
  const size_t F_ATTN = 26900000;   // bf16 [n][256]
  const size_t F_TMP = 28100000;    // fp32 [n][256]
  const size_t F_SRC1 = 30500000;   // fp32 [n][256]
  const size_t F_SRC1B = 32900000;  // bf16 [n][256]
  const size_t F_FF1 = 34100000;    // bf16 [n][1024]
  const size_t F_FF2 = 38900000;    // fp32 [n][256] -> end 41,259,296 fl

  bf16* wkbase = (bf16*)(ws + F_WT);
  bf16* wk1 = wkbase + 0;
  bf16* wk2 = wkbase + 24576;
  bf16* wkf2 = wkbase + 466944;
  bf16* wkcf = wkbase + 540672;
  bf16* wkfh1 = wkbase + 830976;
  bf16* wl_oa = wkbase + 1125888;
  bf16* wl_val = wkbase + 1150464;
  bf16* wl_out = wkbase + 1216000;
  bf16* wl_ff1 = wkbase + 1281536;
  bf16* wl_ff2 = wkbase + 1543680;
  bf16* wk7 = wkbase + 1805824;
  bf16* corrb = (bf16*)(ws + F_CORR);
  bf16* f1t = (bf16*)(ws + F_F1T);
  bf16* f2t = (bf16*)(ws + F_F2T);
  bf16* qb = (bf16*)(ws + F_QB);
  bf16* cf = (bf16*)(ws + F_CF);
  bf16* col7 = (bf16*)(ws + F_COL7);
  bf16* cor1 = (bf16*)(ws + F_COR1);
  bf16* flo1 = (bf16*)(ws + F_FLO1);
  bf16* cat = (bf16*)(ws + F_CAT);
  bf16* mf = (bf16*)(ws + F_MF);
  bf16* fh1 = (bf16*)(ws + F_FH1);
  bf16* attnb = (bf16*)(ws + F_ATTN);
  bf16* src1b = (bf16*)(ws + F_SRC1B);
  bf16* ff1b = (bf16*)(ws + F_FF1);

  // 1. weight pack (independent of everything)
  WtSegs segs;
  const float* srcs[12] = {wc1, wc2, wf2, wcf, wfh1, w_off, w_aw, w_val, w_out, w_ff1, w_ff2, wf1};
  unsigned offs[12] = {0, 24576, 466944, 540672, 830976, 1125888, 1142272, 1150464, 1216000, 1281536, 1543680, 1805824};
  int couts[12] = {256, 192, 64, 126, 256, 64, 32, 256, 256, 1024, 256, 128};
  int cins[12] = {81, 256, 128, 256, 128, 256, 256, 256, 256, 256, 1024, 2};
  int kps[12] = {96, 256, 128, 256, 128, 256, 256, 256, 256, 256, 1024, 128};
  int ks2[12] = {1, 9, 9, 9, 9, 1, 1, 1, 1, 1, 1, 0};
  unsigned cum = 0;
  for (int i = 0; i < 12; ++i) {
    segs.src[i] = srcs[i];
    segs.dstOff[i] = offs[i];
    segs.Cout[i] = couts[i];
    segs.Cin[i] = cins[i];
    segs.KP[i] = kps[i];
    segs.KS2[i] = ks2[i];
    segs.cum[i] = cum;
    cum += (unsigned)((ks2[i] ? ks2[i] : 1) * couts[i] * kps[i]);
  }
  segs.cum[12] = cum;
  wt_all_k<<<dim3((cum + 255) / 256), 256, 0, stream>>>(segs, wkbase);

  // 2-4. prep (transposes + pos), im2col7, copy_flow
  prep_k<<<dim3(36, 4, 8), 256, 0, stream>>>(fmap1, fmap2, ws + F_SRCT, f1t, qb, f2t);
  im2col7_k<<<dim3(4608), 256, 0, stream>>>(flow, col7);
  copy_flow_k<<<dim3(72), 256, 0, stream>>>(flow, mf);

  // 5-6. corr + lookup
  corr_mfma_k<<<dim3(36, 18, 4), 256, 0, stream>>>(f1t, f2t, corrb);
  corr_lookup_k<<<dim3(3456), 256, 0, stream>>>(corrb, flow, cf);

  auto setseg = [](GSegs& G, int i, const bf16* in, const bf16* wt, const float* bias,
                   const float* bias2, int split, float* outf, bf16* outb, int O, int KP,
                   int taps, int OStride, int OOff, int relu) {
    G.in[i] = in; G.wt[i] = wt; G.bias[i] = bias; G.bias2[i] = bias2; G.split[i] = split;
    G.outf[i] = outf; G.outb[i] = outb; G.O[i] = O; G.KP[i] = KP; G.taps[i] = taps;
    G.OStride[i] = OStride; G.OOff[i] = OOff; G.relu[i] = relu;
    G.nTn[i] = (O + 63) / 64;
  };
  auto finseg = [](GSegs& G, int n) {
    int cumb = 0;
    for (int i = 0; i < 4; ++i) {
      if (i < n) { G.blkStart[i] = cumb; cumb += G.nTn[i] * 72; }
      else G.blkStart[i] = 0x7fffffff;
    }
    G.nseg = n;
    return cumb;
  };

  // 7. GROUP A: wc1, conv7-linear, off|aw, val
  GSegs GA;
  setseg(GA, 0, cf, wk1, bc1, nullptr, 1 << 30, nullptr, cor1, 256, 96, 1, 256, 0, 1);
  setseg(GA, 1, col7, wk7, bf1, nullptr, 1 << 30, nullptr, flo1, 128, 128, 1, 128, 0, 1);
  setseg(GA, 2, qb, wl_oa, b_off, b_aw, 64, ws + F_OA, nullptr, 96, 256, 1, 96, 0, 0);
  setseg(GA, 3, f1t, wl_val, b_val, nullptr, 1 << 30, ws + F_VAL, nullptr, 256, 256, 1, 256, 0, 0);
  int nblkA = finseg(GA, 4);
  gemm_group_k<<<dim3(nblkA), 256, 0, stream>>>(GA);

  // 8. deform
  deform_k<<<dim3(9216), 256, 0, stream>>>(ws + F_VAL, ws + F_OA, attnb);

  // 9. GROUP B: wc2, wf2, out-proj
  GSegs GB;
  setseg(GB, 0, cor1, wk2, bc2, nullptr, 1 << 30, nullptr, cat, 192, 256, 9, 256, 0, 1);
  setseg(GB, 1, flo1, wkf2, bf2, nullptr, 1 << 30, nullptr, cat, 64, 128, 9, 256, 192, 1);
  setseg(GB, 2, attnb, wl_out, b_out, nullptr, 1 << 30, ws + F_TMP, nullptr, 256, 256, 1, 256, 0, 0);
  int nblkB = finseg(GB, 3);
  gemm_group_k<<<dim3(nblkB), 256, 0, stream>>>(GB);

  // 10. LN1
  ln_add_k<<<dim3(9216), 256, 0, stream>>>(ws + F_TMP, ws + F_SRCT, ln1_g, ln1_b, ws + F_SRC1, src1b);

  // 11. GROUP C: wcf, ff1
  GSegs GC;
  setseg(GC, 0, cat, wkcf, bcf, nullptr, 1 << 30, nullptr, mf, 126, 256, 9, 128, 0, 1);
  setseg(GC, 1, src1b, wl_ff1, b_ff1, nullptr, 1 << 30, nullptr, ff1b, 1024, 256, 1, 1024, 0, 1);
  int nblkC = finseg(GC, 2);
  gemm_group_k<<<dim3(nblkC), 256, 0, stream>>>(GC);

  // 12. GROUP D: wfh1, ff2
  GSegs GD;
  setseg(GD, 0, mf, wkfh1, bfh1, nullptr, 1 << 30, nullptr, fh1, 256, 128, 9, 256, 0, 1);
  setseg(GD, 1, ff1b, wl_ff2, b_ff2, nullptr, 1 << 30, ws + F_FF2, nullptr, 256, 1024, 1, 256, 0, 0);
  int nblkD = finseg(GD, 2);
  gemm_group_k<<<dim3(nblkD), 256, 0, stream>>>(GD);

  // 13-14. flow head tail + LN2
  convfh2_k<<<dim3(2304), 256, 0, stream>>>(fh1, wfh2, bfh2, out_df);
  ln_add_k<<<dim3(9216), 256, 0, stream>>>(ws + F_FF2, ws + F_SRC1, ln2_g, ln2_b, out_src, nullptr);

  (void)in_sizes; (void)n_in; (void)out_size; (void)ws_size;
}

// Round 9
// 285.969 us; speedup vs baseline: 1.2660x; 1.0501x over previous
//
#include <hip/hip_runtime.h>
#include <hip/hip_bf16.h>
#include <math.h>

#define HH 48
#define WW 48
#define HW 2304
#define BB 4
#define CC 256

typedef __hip_bfloat16 bf16;
typedef __attribute__((ext_vector_type(8))) short s8v;
typedef __attribute__((ext_vector_type(4))) float f4v;

__device__ inline float bf2f(short u) {
  unsigned v = ((unsigned)(unsigned short)u) << 16;
  return __builtin_bit_cast(float, v);
}

// ---------------- prep: z<4 -> fmap2 transpose; z>=4 -> fmap1 transpose + srcT/qb ----
__global__ __launch_bounds__(256) void prep_k(const float* __restrict__ fmap1,
                                              const float* __restrict__ fmap2,
                                              float* __restrict__ srcT,
                                              bf16* __restrict__ f1t,
                                              bf16* __restrict__ qb,
                                              bf16* __restrict__ f2t) {
  __shared__ float t[64][65];
  int z = blockIdx.z;
  int p0 = blockIdx.x * 64, c0 = blockIdx.y * 64;
  int b = z & 3;
  const float* src = (z < 4) ? fmap2 : fmap1;
  const float* inb = src + ((size_t)b * CC + c0) * HW + p0;
#pragma unroll
  for (int i = 0; i < 16; ++i) {
    int idx = threadIdx.x + i * 256;
    int c = idx >> 6, p = idx & 63;
    t[c][p] = inb[(size_t)c * HW + p];
  }
  __syncthreads();
  if (z < 4) {
    bf16* ob = f2t + ((size_t)b * HW + p0) * 256 + c0;
#pragma unroll
    for (int i = 0; i < 16; ++i) {
      int idx = threadIdx.x + i * 256;
      int p = idx >> 6, c = idx & 63;
      ob[(size_t)p * 256 + c] = (bf16)t[c][p];
    }
  } else {
    const float TWO_PI = 6.283185307179586f;
#pragma unroll
    for (int i = 0; i < 16; ++i) {
      int idx = threadIdx.x + i * 256;
      int pl = idx >> 6, cl = idx & 63;
      int c = c0 + cl;
      int p = p0 + pl;
      int y = p / WW, x = p % WW;
      float s = t[cl][pl];
      int axis = c >> 7;
      int cc = c & 127;
      int mm = cc >> 1;
      float coord = (axis ? ((float)x + 0.5f) : ((float)y + 0.5f)) * (TWO_PI / (48.f + 1e-6f));
      float tp = exp2f((float)mm * (13.287712379549449f / 64.f));
      float a = coord / tp;
      float pv = (cc & 1) ? cosf(a) : sinf(a);
      size_t o = ((size_t)b * HW + p) * 256 + c;
      srcT[o] = s;
      f1t[o] = (bf16)s;
      qb[o] = (bf16)(s + pv);
    }
  }
}

// ---------------- corr MFMA 128x64, reg-prefetch + LDS dbuf pipeline ----------------
__global__ __launch_bounds__(256) void corr_mfma_k(const bf16* __restrict__ f1t,
                                                   const bf16* __restrict__ f2t,
                                                   bf16* __restrict__ corr) {
  int b = blockIdx.z;
  int m0 = blockIdx.y * 128, n0 = blockIdx.x * 64;
  __shared__ short As[2][128][64];
  __shared__ short Bs[2][64][64];
  int tid = threadIdx.x;
  int arl = tid >> 1, asl = (tid & 1) * 4;
  int brl = tid >> 2, bsl = (tid & 3) * 2;
  int wave = tid >> 6, lane = tid & 63;
  int wm = (wave >> 1) * 64, wn = (wave & 1) * 32;
  int fl = lane & 15, fk8 = lane >> 4;
  f4v acc[4][2] = {};
  const bf16* arow = f1t + ((size_t)b * HW + m0 + arl) * 256;
  const bf16* brow = f2t + ((size_t)b * HW + n0 + brl) * 256;
  uint4 apre[4], bpre[2];
#pragma unroll
  for (int q = 0; q < 4; ++q) apre[q] = *(const uint4*)(arow + (asl + q) * 8);
#pragma unroll
  for (int q = 0; q < 2; ++q) bpre[q] = *(const uint4*)(brow + (bsl + q) * 8);
  int cur = 0;
  for (int st = 0; st < 4; ++st) {
#pragma unroll
    for (int q = 0; q < 4; ++q) {
      int sr = asl + q;
      *(uint4*)&As[cur][arl][((sr ^ (arl & 7))) * 8] = apre[q];
    }
#pragma unroll
    for (int q = 0; q < 2; ++q) {
      int sr = bsl + q;
      *(uint4*)&Bs[cur][brl][((sr ^ (brl & 7))) * 8] = bpre[q];
    }
    if (st < 3) {
      int c0 = (st + 1) * 64;
#pragma unroll
      for (int q = 0; q < 4; ++q) apre[q] = *(const uint4*)(arow + c0 + (asl + q) * 8);
#pragma unroll
      for (int q = 0; q < 2; ++q) bpre[q] = *(const uint4*)(brow + c0 + (bsl + q) * 8);
    }
    __syncthreads();
#pragma unroll
    for (int cc = 0; cc < 2; ++cc) {
      s8v af[4], bfr[2];
#pragma unroll
      for (int i = 0; i < 4; ++i) {
        int ar = wm + i * 16 + fl;
        af[i] = *(const s8v*)&As[cur][ar][(((cc * 4 + fk8) ^ (ar & 7))) * 8];
      }
#pragma unroll
      for (int j = 0; j < 2; ++j) {
        int br = wn + j * 16 + fl;
        bfr[j] = *(const s8v*)&Bs[cur][br][(((cc * 4 + fk8) ^ (br & 7))) * 8];
      }
#pragma unroll
      for (int i = 0; i < 4; ++i)
#pragma unroll
        for (int j = 0; j < 2; ++j)
          acc[i][j] = __builtin_amdgcn_mfma_f32_16x16x32_bf16(af[i], bfr[j], acc[i][j], 0, 0, 0);
    }
    cur ^= 1;
  }
  bf16* outp = corr + ((size_t)b * HW + m0) * HW + n0;
#pragma unroll
  for (int j = 0; j < 2; ++j) {
    int o = wn + j * 16 + fl;
#pragma unroll
    for (int i = 0; i < 4; ++i)
#pragma unroll
      for (int r = 0; r < 4; ++r) {
        int m = wm + i * 16 + fk8 * 4 + r;
        outp[(size_t)m * HW + o] = (bf16)(acc[i][j][r] * 0.0625f);
      }
  }
}

// ---------------- 81-tap bilinear correlation lookup -> [n][96] bf16 ----
__global__ __launch_bounds__(256) void corr_lookup_k(const bf16* __restrict__ corr,
                                                     const float* __restrict__ flow,
                                                     bf16* __restrict__ cf) {
  int g = blockIdx.x * 256 + threadIdx.x;  // n*96 + t
  int t = g % 96;
  int n = g / 96;
  if (t >= 81) { cf[g] = (bf16)0.f; return; }
  int b = n / HW;
  int p = n % HW;
  int y = p / WW, x = p % WW;
  float fx = flow[((size_t)b * 2 + 0) * HW + p];
  float fy = flow[((size_t)b * 2 + 1) * HW + p];
  float px = (float)x + fx + (float)(t / 9 - 4);
  float py = (float)y + fy + (float)(t % 9 - 4);
  const bf16* row = corr + (size_t)n * HW;
  float x0f = floorf(px), y0f = floorf(py);
  int x0 = (int)x0f, y0 = (int)y0f;
  float wx = px - x0f, wy = py - y0f;
  float acc = 0.f;
  if ((unsigned)x0 < WW && (unsigned)y0 < HH) acc += (float)row[y0 * WW + x0] * (1.f - wx) * (1.f - wy);
  if ((unsigned)(x0 + 1) < WW && (unsigned)y0 < HH) acc += (float)row[y0 * WW + x0 + 1] * wx * (1.f - wy);
  if ((unsigned)x0 < WW && (unsigned)(y0 + 1) < HH) acc += (float)row[(y0 + 1) * WW + x0] * (1.f - wx) * wy;
  if ((unsigned)(x0 + 1) < WW && (unsigned)(y0 + 1) < HH) acc += (float)row[(y0 + 1) * WW + x0 + 1] * wx * wy;
  cf[g] = (bf16)acc;
}

// ---------------- fused weight conversion: 12 segments (KS2==0 => conv7 repack) ----
struct WtSegs {
  const float* src[12];
  unsigned dstOff[12];
  int Cout[12], Cin[12], KP[12], KS2[12];
  unsigned cum[13];
};

__global__ __launch_bounds__(256) void wt_all_k(WtSegs s, bf16* __restrict__ base) {
  unsigned idx = blockIdx.x * 256 + threadIdx.x;
  if (idx >= s.cum[12]) return;
  int seg = 0;
#pragma unroll
  for (int i = 1; i < 12; ++i)
    if (idx >= s.cum[i]) seg = i;
  unsigned r = idx - s.cum[seg];
  int KP = s.KP[seg], Cout = s.Cout[seg], Cin = s.Cin[seg], KS2 = s.KS2[seg];
  int c = r % KP;
  int o = (r / KP) % Cout;
  int t = r / (KP * Cout);
  float v;
  if (KS2 == 0) {
    int cc = c >> 6, tt = c & 63;
    v = (tt < 49) ? s.src[seg][((size_t)o * 2 + cc) * 49 + tt] : 0.f;
  } else {
    v = (c < Cin) ? s.src[seg][((size_t)o * Cin + c) * KS2 + t] : 0.f;
  }
  base[s.dstOff[seg] + r] = (bf16)v;
}

// ---------------- im2col for 7x7 pad3 conv on flow: col7[n][128] bf16 ----
__global__ __launch_bounds__(256) void im2col7_k(const float* __restrict__ flow,
                                                 bf16* __restrict__ col7) {
  int g = blockIdx.x * 256 + threadIdx.x;
  int kp = g & 127;
  int n = g >> 7;
  int b = n / HW;
  int p = n % HW;
  int y = p / WW, x = p % WW;
  int cc = kp >> 6, tt = kp & 63;
  float v = 0.f;
  if (tt < 49) {
    int ky = tt / 7, kx = tt % 7;
    int yy = y + ky - 3, xx = x + kx - 3;
    if ((unsigned)yy < (unsigned)HH && (unsigned)xx < (unsigned)WW)
      v = flow[((size_t)b * 2 + cc) * HW + yy * WW + xx];
  }
  col7[g] = (bf16)v;
}

// ---------------- grouped GEMM with reg-prefetch + LDS dbuf pipeline ----------------
struct GSegs {
  const bf16* in[4];
  const bf16* wt[4];
  const float* bias[4];
  const float* bias2[4];
  float* outf[4];
  bf16* outb[4];
  int split[4], O[4], KP[4], taps[4], OStride[4], OOff[4], relu[4], nTn[4];
  int blkStart[4];
  int nseg;
};

__global__ __launch_bounds__(256) void gemm_group_k(GSegs s) {
  int blk = blockIdx.x;
  int seg = 0;
#pragma unroll
  for (int i = 1; i < 4; ++i)
    if (i < s.nseg && blk >= s.blkStart[i]) seg = i;
  int rel = blk - s.blkStart[seg];
  int nTn = s.nTn[seg];
  int bm = rel / nTn, bn = rel % nTn;
  int m0 = bm * 128, n0 = bn * 64;
  int KP = s.KP[seg], O = s.O[seg], taps = s.taps[seg];
  const bf16* in = s.in[seg];
  const bf16* wt = s.wt[seg];

  __shared__ short As[2][128][64];
  __shared__ short Bs[2][64][64];
  int tid = threadIdx.x;
  int arl = tid >> 1, asl = (tid & 1) * 4;
  int brl = tid >> 2, bsl = (tid & 3) * 2;
  int wave = tid >> 6, lane = tid & 63;
  int wm = (wave >> 1) * 64, wn = (wave & 1) * 32;
  int fl = lane & 15, fk8 = lane >> 4;
  f4v acc[4][2] = {};
  int m = m0 + arl;
  int b = m / HW;
  int p = m - b * HW;
  int y = p / WW, x = p - y * WW;
  int wo = n0 + brl;
  bool wvalid = wo < O;
  int wo_c = wvalid ? wo : 0;

  int nc0 = (KP + 63) >> 6;
  int S = taps * nc0;
  uint4 apre[4], bpre[2];

  auto load_stage = [&](int st) {
    int t = st / nc0;
    int c0 = (st - t * nc0) * 64;
    int yy = y, xx = x;
    bool valid = true;
    if (taps == 9) {
      int ky = t / 3, kx = t - ky * 3;
      yy = y + ky - 1;
      xx = x + kx - 1;
      valid = ((unsigned)yy < (unsigned)HH) & ((unsigned)xx < (unsigned)WW);
    }
    const bf16* arow = in + ((size_t)b * HW + yy * WW + xx) * KP;
    const bf16* wrow = wt + ((size_t)t * O + wo_c) * KP;
#pragma unroll
    for (int q = 0; q < 4; ++q) {
      int col = c0 + (asl + q) * 8;
      uint4 v = {0u, 0u, 0u, 0u};
      if (valid && col < KP) v = *(const uint4*)(arow + col);
      apre[q] = v;
    }
#pragma unroll
    for (int q = 0; q < 2; ++q) {
      int col = c0 + (bsl + q) * 8;
      uint4 v = {0u, 0u, 0u, 0u};
      if (wvalid && col < KP) v = *(const uint4*)(wrow + col);
      bpre[q] = v;
    }
  };

  load_stage(0);
  int cur = 0;
  for (int st = 0; st < S; ++st) {
#pragma unroll
    for (int q = 0; q < 4; ++q) {
      int sr = asl + q;
      *(uint4*)&As[cur][arl][((sr ^ (arl & 7))) * 8] = apre[q];
    }
#pragma unroll
    for (int q = 0; q < 2; ++q) {
      int sr = bsl + q;
      *(uint4*)&Bs[cur][brl][((sr ^ (brl & 7))) * 8] = bpre[q];
    }
    if (st + 1 < S) load_stage(st + 1);
    __syncthreads();
#pragma unroll
    for (int cc = 0; cc < 2; ++cc) {
      s8v af[4], bfr[2];
#pragma unroll
      for (int i = 0; i < 4; ++i) {
        int ar = wm + i * 16 + fl;
        af[i] = *(const s8v*)&As[cur][ar][(((cc * 4 + fk8) ^ (ar & 7))) * 8];
      }
#pragma unroll
      for (int j = 0; j < 2; ++j) {
        int br = wn + j * 16 + fl;
        bfr[j] = *(const s8v*)&Bs[cur][br][(((cc * 4 + fk8) ^ (br & 7))) * 8];
      }
#pragma unroll
      for (int i = 0; i < 4; ++i)
#pragma unroll
        for (int j = 0; j < 2; ++j)
          acc[i][j] = __builtin_amdgcn_mfma_f32_16x16x32_bf16(af[i], bfr[j], acc[i][j], 0, 0, 0);
    }
    cur ^= 1;
  }
  int OStride = s.OStride[seg], OOff = s.OOff[seg], relu = s.relu[seg], split = s.split[seg];
  const float* bias = s.bias[seg];
  const float* bias2 = s.bias2[seg];
  float* outf = s.outf[seg];
  bf16* outb = s.outb[seg];
#pragma unroll
  for (int j = 0; j < 2; ++j) {
    int o = n0 + wn + j * 16 + fl;
    if (o < O) {
      float bsv = (bias2 != nullptr && o >= split) ? bias2[o - split] : bias[o];
#pragma unroll
      for (int i = 0; i < 4; ++i)
#pragma unroll
        for (int r = 0; r < 4; ++r) {
          int mm = m0 + wm + i * 16 + fk8 * 4 + r;
          float v = acc[i][j][r] + bsv;
          if (relu) v = fmaxf(v, 0.f);
          if (outb) outb[(size_t)mm * OStride + OOff + o] = (bf16)v;
          else outf[(size_t)mm * OStride + OOff + o] = v;
        }
    }
  }
}

// ---------------- final 3x3 conv 256->2, wave-per-pixel, LDS weights ----------------
__global__ __launch_bounds__(256) void convfh2_k(const bf16* __restrict__ fh1,
                                                 const float* __restrict__ w,
                                                 const float* __restrict__ bias,
                                                 float* __restrict__ out) {
  __shared__ float wl[4608];
  int tid = threadIdx.x;
#pragma unroll
  for (int i = tid; i < 4608; i += 256) {
    int o2 = i & 1;
    int t = (i >> 1) % 9;
    int c = i / 18;
    wl[i] = w[((size_t)o2 * 256 + c) * 9 + t];
  }
  __syncthreads();
  int wave = tid >> 6, lane = tid & 63;
  int pix = blockIdx.x * 4 + wave;
  int b = pix / HW;
  int q = pix % HW;
  int y = q / WW, x = q % WW;
  int c0 = lane * 4;
  float a0 = 0.f, a1 = 0.f;
#pragma unroll
  for (int ky = 0; ky < 3; ++ky) {
    int yy = y + ky - 1;
    if ((unsigned)yy >= (unsigned)HH) continue;
#pragma unroll
    for (int kx = 0; kx < 3; ++kx) {
      int xx = x + kx - 1;
      if ((unsigned)xx >= (unsigned)WW) continue;
      int t = ky * 3 + kx;
      const bf16* row = fh1 + ((size_t)b * HW + yy * WW + xx) * 256 + c0;
      ushort4 v = *(const ushort4*)row;
      unsigned short vv[4] = {v.x, v.y, v.z, v.w};
#pragma unroll
      for (int j = 0; j < 4; ++j) {
        float fv = bf2f((short)vv[j]);
        float2 wp = *(const float2*)&wl[((c0 + j) * 9 + t) * 2];
        a0 += fv * wp.x;
        a1 += fv * wp.y;
      }
    }
  }
#pragma unroll
  for (int offl = 32; offl > 0; offl >>= 1) {
    a0 += __shfl_xor(a0, offl);
    a1 += __shfl_xor(a1, offl);
  }
  if (lane == 0) {
    out[(size_t)b * 2 * HW + q] = a0 + bias[0];
    out[((size_t)b * 2 + 1) * HW + q] = a1 + bias[1];
  }
}

// ---------------- copy flow into mf cols 126,127 ----------------
__global__ void copy_flow_k(const float* __restrict__ flow, bf16* __restrict__ mf) {
  int g = blockIdx.x * 256 + threadIdx.x;
  int p = g % HW;
  int c = (g / HW) % 2;
  int b = g / (2 * HW);
  mf[((size_t)b * HW + p) * 128 + 126 + c] = (bf16)flow[g];
}

// ---------------- deformable sampling with inline softmax; oa=[n][96] (off|aw) ----
__global__ __launch_bounds__(256) void deform_k(const float* __restrict__ val,
                                                const float* __restrict__ oa,
                                                bf16* __restrict__ attn) {
  int g = blockIdx.x * 256 + threadIdx.x;
  int d = g & 31;
  int nh = g >> 5;
  int h = nh & 7;
  int n = nh >> 3;
  int b = n / HW;
  int p = n % HW;
  int y = p / WW, x = p % WW;
  const float* ap = oa + (size_t)n * 96 + 64 + h * 4;
  float l0 = ap[0], l1 = ap[1], l2 = ap[2], l3 = ap[3];
  float mx = fmaxf(fmaxf(l0, l1), fmaxf(l2, l3));
  float e0 = expf(l0 - mx), e1 = expf(l1 - mx), e2 = expf(l2 - mx), e3 = expf(l3 - mx);
  float inv = 1.f / (e0 + e1 + e2 + e3);
  float wts[4] = {e0 * inv, e1 * inv, e2 * inv, e3 * inv};
  const float* offp = oa + (size_t)n * 96 + h * 8;
  const float* vb = val + (size_t)b * HW * 256 + h * 32 + d;
  float acc = 0.f;
#pragma unroll
  for (int pt = 0; pt < 4; ++pt) {
    float ox = offp[pt * 2 + 0];
    float oy = offp[pt * 2 + 1];
    float w = wts[pt];
    float px = (float)x + ox, py = (float)y + oy;
    float x0f = floorf(px), y0f = floorf(py);
    int x0 = (int)x0f, y0 = (int)y0f;
    float wx = px - x0f, wy = py - y0f;
    float s = 0.f;
    if ((unsigned)x0 < WW && (unsigned)y0 < HH)
      s += vb[(size_t)(y0 * WW + x0) * 256] * (1.f - wx) * (1.f - wy);
    if ((unsigned)(x0 + 1) < WW && (unsigned)y0 < HH)
      s += vb[(size_t)(y0 * WW + x0 + 1) * 256] * wx * (1.f - wy);
    if ((unsigned)x0 < WW && (unsigned)(y0 + 1) < HH)
      s += vb[(size_t)((y0 + 1) * WW + x0) * 256] * (1.f - wx) * wy;
    if ((unsigned)(x0 + 1) < WW && (unsigned)(y0 + 1) < HH)
      s += vb[(size_t)((y0 + 1) * WW + x0 + 1) * 256] * wx * wy;
    acc += w * s;
  }
  attn[(size_t)n * 256 + h * 32 + d] = (bf16)acc;
}

// ---------------- fused residual add + LayerNorm over 256 (optional bf16 copy) ----
__global__ __launch_bounds__(256) void ln_add_k(const float* __restrict__ A,
                                                const float* __restrict__ Bv,
                                                const float* __restrict__ g,
                                                const float* __restrict__ be,
                                                float* __restrict__ out,
                                                bf16* __restrict__ outb) {
  int n = blockIdx.x;
  int c = threadIdx.x;
  float v = A[(size_t)n * 256 + c] + Bv[(size_t)n * 256 + c];
  float s1 = v, s2 = v * v;
#pragma unroll
  for (int o = 32; o > 0; o >>= 1) {
    s1 += __shfl_down(s1, o);
    s2 += __shfl_down(s2, o);
  }
  __shared__ float r1[4], r2[4], mv[2];
  int wid = c >> 6, lane = c & 63;
  if (lane == 0) {
    r1[wid] = s1;
    r2[wid] = s2;
  }
  __syncthreads();
  if (c == 0) {
    float a = r1[0] + r1[1] + r1[2] + r1[3];
    float q2 = r2[0] + r2[1] + r2[2] + r2[3];
    float mean = a * (1.f / 256.f);
    mv[0] = mean;
    mv[1] = q2 * (1.f / 256.f) - mean * mean;
  }
  __syncthreads();
  float mean = mv[0], var = mv[1];
  float r = (v - mean) * rsqrtf(var + 1e-5f) * g[c] + be[c];
  out[(size_t)n * 256 + c] = r;
  if (outb) outb[(size_t)n * 256 + c] = (bf16)r;
}

extern "C" void kernel_launch(void* const* d_in, const int* in_sizes, int n_in,
                              void* d_out, int out_size, void* d_ws, size_t ws_size,
                              hipStream_t stream) {
  const float* fmap1 = (const float*)d_in[0];
  const float* fmap2 = (const float*)d_in[1];
  const float* flow = (const float*)d_in[2];
  const float* wc1 = (const float*)d_in[3];
  const float* bc1 = (const float*)d_in[4];
  const float* wc2 = (const float*)d_in[5];
  const float* bc2 = (const float*)d_in[6];
  const float* wf1 = (const float*)d_in[7];
  const float* bf1 = (const float*)d_in[8];
  const float* wf2 = (const float*)d_in[9];
  const float* bf2 = (const float*)d_in[10];
  const float* wcf = (const float*)d_in[11];
  const float* bcf = (const float*)d_in[12];
  const float* wfh1 = (const float*)d_in[13];
  const float* bfh1 = (const float*)d_in[14];
  const float* wfh2 = (const float*)d_in[15];
  const float* bfh2 = (const float*)d_in[16];
  const float* w_off = (const float*)d_in[17];
  const float* b_off = (const float*)d_in[18];
  const float* w_aw = (const float*)d_in[19];
  const float* b_aw = (const float*)d_in[20];
  const float* w_val = (const float*)d_in[21];
  const float* b_val = (const float*)d_in[22];
  const float* w_out = (const float*)d_in[23];
  const float* b_out = (const float*)d_in[24];
  const float* ln1_g = (const float*)d_in[25];
  const float* ln1_b = (const float*)d_in[26];
  const float* w_ff1 = (const float*)d_in[27];
  const float* b_ff1 = (const float*)d_in[28];
  const float* w_ff2 = (const float*)d_in[29];
  const float* b_ff2 = (const float*)d_in[30];
  const float* ln2_g = (const float*)d_in[31];
  const float* ln2_b = (const float*)d_in[32];

  float* ws = (float*)d_ws;
  float* out_src = (float*)d_out;
  float* out_df = out_src + (size_t)BB * HW * CC;

  // ---- workspace layout (float offsets), fully de-aliased (~165 MB) ----
  const size_t F_WT = 0;
  const size_t F_CORR = 1000000;
  const size_t F_F1T = 11700000;
  const size_t F_F2T = 12900000;
  const size_t F_QB = 14100000;
  const size_t F_SRCT = 15300000;
  const size_t F_CF = 17700000;
  const size_t F_COL7 = 18200000;
  const size_t F_COR1 = 18800000;
  const size_t F_FLO1 = 20000000;
  const size_t F_CAT = 20600000;
  const size_t F_MF = 21800000;
  const size_t F_FH1 = 22400000;
  const size_t F_OA = 23600000;
  const size_t F_VAL = 24500000;
  const size_t F_ATTN = 26900000;
  const size_t F_TMP = 28100000;
  const size_t F_SRC1 = 30500000;
  const size_t F_SRC1B = 32900000;
  const size_t F_FF1 = 34100000;
  const size_t F_FF2 = 38900000;

  bf16* wkbase = (bf16*)(ws + F_WT);
  bf16* wk1 = wkbase + 0;
  bf16* wk2 = wkbase + 24576;
  bf16* wkf2 = wkbase + 466944;
  bf16* wkcf = wkbase + 540672;
  bf16* wkfh1 = wkbase + 830976;
  bf16* wl_oa = wkbase + 1125888;
  bf16* wl_val = wkbase + 1150464;
  bf16* wl_out = wkbase + 1216000;
  bf16* wl_ff1 = wkbase + 1281536;
  bf16* wl_ff2 = wkbase + 1543680;
  bf16* wk7 = wkbase + 1805824;
  bf16* corrb = (bf16*)(ws + F_CORR);
  bf16* f1t = (bf16*)(ws + F_F1T);
  bf16* f2t = (bf16*)(ws + F_F2T);
  bf16* qb = (bf16*)(ws + F_QB);
  bf16* cf = (bf16*)(ws + F_CF);
  bf16* col7 = (bf16*)(ws + F_COL7);
  bf16* cor1 = (bf16*)(ws + F_COR1);
  bf16* flo1 = (bf16*)(ws + F_FLO1);
  bf16* cat = (bf16*)(ws + F_CAT);
  bf16* mf = (bf16*)(ws + F_MF);
  bf16* fh1 = (bf16*)(ws + F_FH1);
  bf16* attnb = (bf16*)(ws + F_ATTN);
  bf16* src1b = (bf16*)(ws + F_SRC1B);
  bf16* ff1b = (bf16*)(ws + F_FF1);

  // 1. weight pack
  WtSegs segs;
  const float* srcs[12] = {wc1, wc2, wf2, wcf, wfh1, w_off, w_aw, w_val, w_out, w_ff1, w_ff2, wf1};
  unsigned offs[12] = {0, 24576, 466944, 540672, 830976, 1125888, 1142272, 1150464, 1216000, 1281536, 1543680, 1805824};
  int couts[12] = {256, 192, 64, 126, 256, 64, 32, 256, 256, 1024, 256, 128};
  int cins[12] = {81, 256, 128, 256, 128, 256, 256, 256, 256, 256, 1024, 2};
  int kps[12] = {96, 256, 128, 256, 128, 256, 256, 256, 256, 256, 1024, 128};
  int ks2[12] = {1, 9, 9, 9, 9, 1, 1, 1, 1, 1, 1, 0};
  unsigned cum = 0;
  for (int i = 0; i < 12; ++i) {
    segs.src[i] = srcs[i];
    segs.dstOff[i] = offs[i];
    segs.Cout[i] = couts[i];
    segs.Cin[i] = cins[i];
    segs.KP[i] = kps[i];
    segs.KS2[i] = ks2[i];
    segs.cum[i] = cum;
    cum += (unsigned)((ks2[i] ? ks2[i] : 1) * couts[i] * kps[i]);
  }
  segs.cum[12] = cum;
  wt_all_k<<<dim3((cum + 255) / 256), 256, 0, stream>>>(segs, wkbase);

  // 2-4. prep, im2col7, copy_flow
  prep_k<<<dim3(36, 4, 8), 256, 0, stream>>>(fmap1, fmap2, ws + F_SRCT, f1t, qb, f2t);
  im2col7_k<<<dim3(4608), 256, 0, stream>>>(flow, col7);
  copy_flow_k<<<dim3(72), 256, 0, stream>>>(flow, mf);

  // 5-6. corr + lookup
  corr_mfma_k<<<dim3(36, 18, 4), 256, 0, stream>>>(f1t, f2t, corrb);
  corr_lookup_k<<<dim3(3456), 256, 0, stream>>>(corrb, flow, cf);

  auto setseg = [](GSegs& G, int i, const bf16* in, const bf16* wt, const float* bias,
                   const float* bias2, int split, float* outf, bf16* outb, int O, int KP,
                   int taps, int OStride, int OOff, int relu) {
    G.in[i] = in; G.wt[i] = wt; G.bias[i] = bias; G.bias2[i] = bias2; G.split[i] = split;
    G.outf[i] = outf; G.outb[i] = outb; G.O[i] = O; G.KP[i] = KP; G.taps[i] = taps;
    G.OStride[i] = OStride; G.OOff[i] = OOff; G.relu[i] = relu;
    G.nTn[i] = (O + 63) / 64;
  };
  auto finseg = [](GSegs& G, int n) {
    int cumb = 0;
    for (int i = 0; i < 4; ++i) {
      if (i < n) { G.blkStart[i] = cumb; cumb += G.nTn[i] * 72; }
      else G.blkStart[i] = 0x7fffffff;
    }
    G.nseg = n;
    return cumb;
  };

  // 7. GROUP A: wc1, conv7-linear, off|aw, val
  GSegs GA;
  setseg(GA, 0, cf, wk1, bc1, nullptr, 1 << 30, nullptr, cor1, 256, 96, 1, 256, 0, 1);
  setseg(GA, 1, col7, wk7, bf1, nullptr, 1 << 30, nullptr, flo1, 128, 128, 1, 128, 0, 1);
  setseg(GA, 2, qb, wl_oa, b_off, b_aw, 64, ws + F_OA, nullptr, 96, 256, 1, 96, 0, 0);
  setseg(GA, 3, f1t, wl_val, b_val, nullptr, 1 << 30, ws + F_VAL, nullptr, 256, 256, 1, 256, 0, 0);
  int nblkA = finseg(GA, 4);
  gemm_group_k<<<dim3(nblkA), 256, 0, stream>>>(GA);

  // 8. deform
  deform_k<<<dim3(9216), 256, 0, stream>>>(ws + F_VAL, ws + F_OA, attnb);

  // 9. GROUP B: wc2, wf2, out-proj
  GSegs GB;
  setseg(GB, 0, cor1, wk2, bc2, nullptr, 1 << 30, nullptr, cat, 192, 256, 9, 256, 0, 1);
  setseg(GB, 1, flo1, wkf2, bf2, nullptr, 1 << 30, nullptr, cat, 64, 128, 9, 256, 192, 1);
  setseg(GB, 2, attnb, wl_out, b_out, nullptr, 1 << 30, ws + F_TMP, nullptr, 256, 256, 1, 256, 0, 0);
  int nblkB = finseg(GB, 3);
  gemm_group_k<<<dim3(nblkB), 256, 0, stream>>>(GB);

  // 10. LN1
  ln_add_k<<<dim3(9216), 256, 0, stream>>>(ws + F_TMP, ws + F_SRCT, ln1_g, ln1_b, ws + F_SRC1, src1b);

  // 11. GROUP C: wcf, ff1
  GSegs GC;
  setseg(GC, 0, cat, wkcf, bcf, nullptr, 1 << 30, nullptr, mf, 126, 256, 9, 128, 0, 1);
  setseg(GC, 1, src1b, wl_ff1, b_ff1, nullptr, 1 << 30, nullptr, ff1b, 1024, 256, 1, 1024, 0, 1);
  int nblkC = finseg(GC, 2);
  gemm_group_k<<<dim3(nblkC), 256, 0, stream>>>(GC);

  // 12. GROUP D: wfh1, ff2
  GSegs GD;
  setseg(GD, 0, mf, wkfh1, bfh1, nullptr, 1 << 30, nullptr, fh1, 256, 128, 9, 256, 0, 1);
  setseg(GD, 1, ff1b, wl_ff2, b_ff2, nullptr, 1 << 30, ws + F_FF2, nullptr, 256, 1024, 1, 256, 0, 0);
  int nblkD = finseg(GD, 2);
  gemm_group_k<<<dim3(nblkD), 256, 0, stream>>>(GD);

  // 13-14. flow head tail + LN2
  convfh2_k<<<dim3(2304), 256, 0, stream>>>(fh1, wfh2, bfh2, out_df);
  ln_add_k<<<dim3(9216), 256, 0, stream>>>(ws + F_FF2, ws + F_SRC1, ln2_g, ln2_b, out_src, nullptr);

  (void)in_sizes; (void)n_in; (void)out_size; (void)ws_size;
}

// Round 10
// 284.298 us; speedup vs baseline: 1.2734x; 1.0059x over previous
//
#include <hip/hip_runtime.h>
#include <hip/hip_bf16.h>
#include <math.h>

#define HH 48
#define WW 48
#define HW 2304
#define BB 4
#define CC 256

typedef __hip_bfloat16 bf16;
typedef __attribute__((ext_vector_type(8))) short s8v;
typedef __attribute__((ext_vector_type(4))) float f4v;

__device__ inline float bf2f(short u) {
  unsigned v = ((unsigned)(unsigned short)u) << 16;
  return __builtin_bit_cast(float, v);
}

// ---------------- prep: z<4 -> fmap2 transpose; z>=4 -> fmap1 transpose + srcT/qb ----
__global__ __launch_bounds__(256) void prep_k(const float* __restrict__ fmap1,
                                              const float* __restrict__ fmap2,
                                              float* __restrict__ srcT,
                                              bf16* __restrict__ f1t,
                                              bf16* __restrict__ qb,
                                              bf16* __restrict__ f2t) {
  __shared__ float t[64][65];
  int z = blockIdx.z;
  int p0 = blockIdx.x * 64, c0 = blockIdx.y * 64;
  int b = z & 3;
  const float* src = (z < 4) ? fmap2 : fmap1;
  const float* inb = src + ((size_t)b * CC + c0) * HW + p0;
#pragma unroll
  for (int i = 0; i < 16; ++i) {
    int idx = threadIdx.x + i * 256;
    int c = idx >> 6, p = idx & 63;
    t[c][p] = inb[(size_t)c * HW + p];
  }
  __syncthreads();
  if (z < 4) {
    bf16* ob = f2t + ((size_t)b * HW + p0) * 256 + c0;
#pragma unroll
    for (int i = 0; i < 16; ++i) {
      int idx = threadIdx.x + i * 256;
      int p = idx >> 6, c = idx & 63;
      ob[(size_t)p * 256 + c] = (bf16)t[c][p];
    }
  } else {
    const float TWO_PI = 6.283185307179586f;
#pragma unroll
    for (int i = 0; i < 16; ++i) {
      int idx = threadIdx.x + i * 256;
      int pl = idx >> 6, cl = idx & 63;
      int c = c0 + cl;
      int p = p0 + pl;
      int y = p / WW, x = p % WW;
      float s = t[cl][pl];
      int axis = c >> 7;
      int cc = c & 127;
      int mm = cc >> 1;
      float coord = (axis ? ((float)x + 0.5f) : ((float)y + 0.5f)) * (TWO_PI / (48.f + 1e-6f));
      float tp = exp2f((float)mm * (13.287712379549449f / 64.f));
      float a = coord / tp;
      float pv = (cc & 1) ? cosf(a) : sinf(a);
      size_t o = ((size_t)b * HW + p) * 256 + c;
      srcT[o] = s;
      f1t[o] = (bf16)s;
      qb[o] = (bf16)(s + pv);
    }
  }
}

// ---------------- corr MFMA 128x64: single-buffer + reg prefetch + LDS-staged epilogue ----
__global__ __launch_bounds__(256) void corr_mfma_k(const bf16* __restrict__ f1t,
                                                   const bf16* __restrict__ f2t,
                                                   bf16* __restrict__ corr) {
  int b = blockIdx.z;
  int m0 = blockIdx.y * 128, n0 = blockIdx.x * 64;
  __shared__ short smem[12288];  // 24 KB: As[128][64] | Bs[64][64]; epilogue reuses as Cs[128][80]
  short* As = smem;
  short* Bs = smem + 128 * 64;
  int tid = threadIdx.x;
  int arl = tid >> 1, asl = (tid & 1) * 4;
  int brl = tid >> 2, bsl = (tid & 3) * 2;
  int wave = tid >> 6, lane = tid & 63;
  int wm = (wave >> 1) * 64, wn = (wave & 1) * 32;
  int fl = lane & 15, fk8 = lane >> 4;
  f4v acc[4][2] = {};
  const bf16* arow = f1t + ((size_t)b * HW + m0 + arl) * 256;
  const bf16* brow = f2t + ((size_t)b * HW + n0 + brl) * 256;
  uint4 apre[4], bpre[2];
#pragma unroll
  for (int q = 0; q < 4; ++q) apre[q] = *(const uint4*)(arow + (asl + q) * 8);
#pragma unroll
  for (int q = 0; q < 2; ++q) bpre[q] = *(const uint4*)(brow + (bsl + q) * 8);
  for (int st = 0; st < 4; ++st) {
#pragma unroll
    for (int q = 0; q < 4; ++q) {
      int sr = asl + q;
      *(uint4*)&As[arl * 64 + ((sr ^ (arl & 7))) * 8] = apre[q];
    }
#pragma unroll
    for (int q = 0; q < 2; ++q) {
      int sr = bsl + q;
      *(uint4*)&Bs[brl * 64 + ((sr ^ (brl & 7))) * 8] = bpre[q];
    }
    if (st < 3) {  // issue next stage's loads; they fly during compute
      int c0 = (st + 1) * 64;
#pragma unroll
      for (int q = 0; q < 4; ++q) apre[q] = *(const uint4*)(arow + c0 + (asl + q) * 8);
#pragma unroll
      for (int q = 0; q < 2; ++q) bpre[q] = *(const uint4*)(brow + c0 + (bsl + q) * 8);
    }
    __syncthreads();
#pragma unroll
    for (int cc = 0; cc < 2; ++cc) {
      s8v af[4], bfr[2];
#pragma unroll
      for (int i = 0; i < 4; ++i) {
        int ar = wm + i * 16 + fl;
        af[i] = *(const s8v*)&As[ar * 64 + (((cc * 4 + fk8) ^ (ar & 7))) * 8];
      }
#pragma unroll
      for (int j = 0; j < 2; ++j) {
        int br = wn + j * 16 + fl;
        bfr[j] = *(const s8v*)&Bs[br * 64 + (((cc * 4 + fk8) ^ (br & 7))) * 8];
      }
#pragma unroll
      for (int i = 0; i < 4; ++i)
#pragma unroll
        for (int j = 0; j < 2; ++j)
          acc[i][j] = __builtin_amdgcn_mfma_f32_16x16x32_bf16(af[i], bfr[j], acc[i][j], 0, 0, 0);
    }
    __syncthreads();
  }
  // epilogue: stage C tile into LDS (row stride 80 bf16, 160B -> 16B-aligned chunks)
  bf16* Cs = (bf16*)smem;
#pragma unroll
  for (int j = 0; j < 2; ++j) {
    int o = wn + j * 16 + fl;
#pragma unroll
    for (int i = 0; i < 4; ++i)
#pragma unroll
      for (int r = 0; r < 4; ++r) {
        int m = wm + i * 16 + fk8 * 4 + r;
        Cs[m * 80 + o] = (bf16)(acc[i][j][r] * 0.0625f);
      }
  }
  __syncthreads();
  bf16* outp = corr + ((size_t)b * HW + m0) * HW + n0;
#pragma unroll
  for (int it = 0; it < 4; ++it) {
    int gi = it * 256 + tid;  // 0..1023 chunks of 16B; 8 chunks/row => full 128B lines
    int r = gi >> 3, ch = gi & 7;
    uint4 v = *(const uint4*)&Cs[r * 80 + ch * 8];
    *(uint4*)(outp + (size_t)r * HW + ch * 8) = v;
  }
}

// ---------------- 81-tap bilinear correlation lookup -> [n][96] bf16 ----
__global__ __launch_bounds__(256) void corr_lookup_k(const bf16* __restrict__ corr,
                                                     const float* __restrict__ flow,
                                                     bf16* __restrict__ cf) {
  int g = blockIdx.x * 256 + threadIdx.x;  // n*96 + t
  int t = g % 96;
  int n = g / 96;
  if (t >= 81) { cf[g] = (bf16)0.f; return; }
  int b = n / HW;
  int p = n % HW;
  int y = p / WW, x = p % WW;
  float fx = flow[((size_t)b * 2 + 0) * HW + p];
  float fy = flow[((size_t)b * 2 + 1) * HW + p];
  float px = (float)x + fx + (float)(t / 9 - 4);
  float py = (float)y + fy + (float)(t % 9 - 4);
  const bf16* row = corr + (size_t)n * HW;
  float x0f = floorf(px), y0f = floorf(py);
  int x0 = (int)x0f, y0 = (int)y0f;
  float wx = px - x0f, wy = py - y0f;
  float acc = 0.f;
  if ((unsigned)x0 < WW && (unsigned)y0 < HH) acc += (float)row[y0 * WW + x0] * (1.f - wx) * (1.f - wy);
  if ((unsigned)(x0 + 1) < WW && (unsigned)y0 < HH) acc += (float)row[y0 * WW + x0 + 1] * wx * (1.f - wy);
  if ((unsigned)x0 < WW && (unsigned)(y0 + 1) < HH) acc += (float)row[(y0 + 1) * WW + x0] * (1.f - wx) * wy;
  if ((unsigned)(x0 + 1) < WW && (unsigned)(y0 + 1) < HH) acc += (float)row[(y0 + 1) * WW + x0 + 1] * wx * wy;
  cf[g] = (bf16)acc;
}

// ---------------- fused weight conversion: 12 segments (KS2==0 => conv7 repack) ----
struct WtSegs {
  const float* src[12];
  unsigned dstOff[12];
  int Cout[12], Cin[12], KP[12], KS2[12];
  unsigned cum[13];
};

__global__ __launch_bounds__(256) void wt_all_k(WtSegs s, bf16* __restrict__ base) {
  unsigned idx = blockIdx.x * 256 + threadIdx.x;
  if (idx >= s.cum[12]) return;
  int seg = 0;
#pragma unroll
  for (int i = 1; i < 12; ++i)
    if (idx >= s.cum[i]) seg = i;
  unsigned r = idx - s.cum[seg];
  int KP = s.KP[seg], Cout = s.Cout[seg], Cin = s.Cin[seg], KS2 = s.KS2[seg];
  int c = r % KP;
  int o = (r / KP) % Cout;
  int t = r / (KP * Cout);
  float v;
  if (KS2 == 0) {
    int cc = c >> 6, tt = c & 63;
    v = (tt < 49) ? s.src[seg][((size_t)o * 2 + cc) * 49 + tt] : 0.f;
  } else {
    v = (c < Cin) ? s.src[seg][((size_t)o * Cin + c) * KS2 + t] : 0.f;
  }
  base[s.dstOff[seg] + r] = (bf16)v;
}

// ---------------- im2col for 7x7 pad3 conv on flow: col7[n][128] bf16 ----
__global__ __launch_bounds__(256) void im2col7_k(const float* __restrict__ flow,
                                                 bf16* __restrict__ col7) {
  int g = blockIdx.x * 256 + threadIdx.x;
  int kp = g & 127;
  int n = g >> 7;
  int b = n / HW;
  int p = n % HW;
  int y = p / WW, x = p % WW;
  int cc = kp >> 6, tt = kp & 63;
  float v = 0.f;
  if (tt < 49) {
    int ky = tt / 7, kx = tt % 7;
    int yy = y + ky - 3, xx = x + kx - 3;
    if ((unsigned)yy < (unsigned)HH && (unsigned)xx < (unsigned)WW)
      v = flow[((size_t)b * 2 + cc) * HW + yy * WW + xx];
  }
  col7[g] = (bf16)v;
}

// ---------------- grouped GEMM with reg-prefetch + LDS dbuf pipeline ----------------
struct GSegs {
  const bf16* in[4];
  const bf16* wt[4];
  const float* bias[4];
  const float* bias2[4];
  float* outf[4];
  bf16* outb[4];
  int split[4], O[4], KP[4], taps[4], OStride[4], OOff[4], relu[4], nTn[4];
  int blkStart[4];
  int nseg;
};

__global__ __launch_bounds__(256) void gemm_group_k(GSegs s) {
  int blk = blockIdx.x;
  int seg = 0;
#pragma unroll
  for (int i = 1; i < 4; ++i)
    if (i < s.nseg && blk >= s.blkStart[i]) seg = i;
  int rel = blk - s.blkStart[seg];
  int nTn = s.nTn[seg];
  int bm = rel / nTn, bn = rel % nTn;
  int m0 = bm * 128, n0 = bn * 64;
  int KP = s.KP[seg], O = s.O[seg], taps = s.taps[seg];
  const bf16* in = s.in[seg];
  const bf16* wt = s.wt[seg];

  __shared__ short As[2][128][64];
  __shared__ short Bs[2][64][64];
  int tid = threadIdx.x;
  int arl = tid >> 1, asl = (tid & 1) * 4;
  int brl = tid >> 2, bsl = (tid & 3) * 2;
  int wave = tid >> 6, lane = tid & 63;
  int wm = (wave >> 1) * 64, wn = (wave & 1) * 32;
  int fl = lane & 15, fk8 = lane >> 4;
  f4v acc[4][2] = {};
  int m = m0 + arl;
  int b = m / HW;
  int p = m - b * HW;
  int y = p / WW, x = p - y * WW;
  int wo = n0 + brl;
  bool wvalid = wo < O;
  int wo_c = wvalid ? wo : 0;

  int nc0 = (KP + 63) >> 6;
  int S = taps * nc0;
  uint4 apre[4], bpre[2];

  auto load_stage = [&](int st) {
    int t = st / nc0;
    int c0 = (st - t * nc0) * 64;
    int yy = y, xx = x;
    bool valid = true;
    if (taps == 9) {
      int ky = t / 3, kx = t - ky * 3;
      yy = y + ky - 1;
      xx = x + kx - 1;
      valid = ((unsigned)yy < (unsigned)HH) & ((unsigned)xx < (unsigned)WW);
    }
    const bf16* arow = in + ((size_t)b * HW + yy * WW + xx) * KP;
    const bf16* wrow = wt + ((size_t)t * O + wo_c) * KP;
#pragma unroll
    for (int q = 0; q < 4; ++q) {
      int col = c0 + (asl + q) * 8;
      uint4 v = {0u, 0u, 0u, 0u};
      if (valid && col < KP) v = *(const uint4*)(arow + col);
      apre[q] = v;
    }
#pragma unroll
    for (int q = 0; q < 2; ++q) {
      int col = c0 + (bsl + q) * 8;
      uint4 v = {0u, 0u, 0u, 0u};
      if (wvalid && col < KP) v = *(const uint4*)(wrow + col);
      bpre[q] = v;
    }
  };

  load_stage(0);
  int cur = 0;
  for (int st = 0; st < S; ++st) {
#pragma unroll
    for (int q = 0; q < 4; ++q) {
      int sr = asl + q;
      *(uint4*)&As[cur][arl][((sr ^ (arl & 7))) * 8] = apre[q];
    }
#pragma unroll
    for (int q = 0; q < 2; ++q) {
      int sr = bsl + q;
      *(uint4*)&Bs[cur][brl][((sr ^ (brl & 7))) * 8] = bpre[q];
    }
    if (st + 1 < S) load_stage(st + 1);
    __syncthreads();
#pragma unroll
    for (int cc = 0; cc < 2; ++cc) {
      s8v af[4], bfr[2];
#pragma unroll
      for (int i = 0; i < 4; ++i) {
        int ar = wm + i * 16 + fl;
        af[i] = *(const s8v*)&As[cur][ar][(((cc * 4 + fk8) ^ (ar & 7))) * 8];
      }
#pragma unroll
      for (int j = 0; j < 2; ++j) {
        int br = wn + j * 16 + fl;
        bfr[j] = *(const s8v*)&Bs[cur][br][(((cc * 4 + fk8) ^ (br & 7))) * 8];
      }
#pragma unroll
      for (int i = 0; i < 4; ++i)
#pragma unroll
        for (int j = 0; j < 2; ++j)
          acc[i][j] = __builtin_amdgcn_mfma_f32_16x16x32_bf16(af[i], bfr[j], acc[i][j], 0, 0, 0);
    }
    cur ^= 1;
  }
  int OStride = s.OStride[seg], OOff = s.OOff[seg], relu = s.relu[seg], split = s.split[seg];
  const float* bias = s.bias[seg];
  const float* bias2 = s.bias2[seg];
  float* outf = s.outf[seg];
  bf16* outb = s.outb[seg];
#pragma unroll
  for (int j = 0; j < 2; ++j) {
    int o = n0 + wn + j * 16 + fl;
    if (o < O) {
      float bsv = (bias2 != nullptr && o >= split) ? bias2[o - split] : bias[o];
#pragma unroll
      for (int i = 0; i < 4; ++i)
#pragma unroll
        for (int r = 0; r < 4; ++r) {
          int mm = m0 + wm + i * 16 + fk8 * 4 + r;
          float v = acc[i][j][r] + bsv;
          if (relu) v = fmaxf(v, 0.f);
          if (outb) outb[(size_t)mm * OStride + OOff + o] = (bf16)v;
          else outf[(size_t)mm * OStride + OOff + o] = v;
        }
    }
  }
}

// ---------------- final 3x3 conv 256->2, wave-per-pixel, LDS weights ----------------
__global__ __launch_bounds__(256) void convfh2_k(const bf16* __restrict__ fh1,
                                                 const float* __restrict__ w,
                                                 const float* __restrict__ bias,
                                                 float* __restrict__ out) {
  __shared__ float wl[4608];
  int tid = threadIdx.x;
#pragma unroll
  for (int i = tid; i < 4608; i += 256) {
    int o2 = i & 1;
    int t = (i >> 1) % 9;
    int c = i / 18;
    wl[i] = w[((size_t)o2 * 256 + c) * 9 + t];
  }
  __syncthreads();
  int wave = tid >> 6, lane = tid & 63;
  int pix = blockIdx.x * 4 + wave;
  int b = pix / HW;
  int q = pix % HW;
  int y = q / WW, x = q % WW;
  int c0 = lane * 4;
  float a0 = 0.f, a1 = 0.f;
#pragma unroll
  for (int ky = 0; ky < 3; ++ky) {
    int yy = y + ky - 1;
    if ((unsigned)yy >= (unsigned)HH) continue;
#pragma unroll
    for (int kx = 0; kx < 3; ++kx) {
      int xx = x + kx - 1;
      if ((unsigned)xx >= (unsigned)WW) continue;
      int t = ky * 3 + kx;
      const bf16* row = fh1 + ((size_t)b * HW + yy * WW + xx) * 256 + c0;
      ushort4 v = *(const ushort4*)row;
      unsigned short vv[4] = {v.x, v.y, v.z, v.w};
#pragma unroll
      for (int j = 0; j < 4; ++j) {
        float fv = bf2f((short)vv[j]);
        float2 wp = *(const float2*)&wl[((c0 + j) * 9 + t) * 2];
        a0 += fv * wp.x;
        a1 += fv * wp.y;
      }
    }
  }
#pragma unroll
  for (int offl = 32; offl > 0; offl >>= 1) {
    a0 += __shfl_xor(a0, offl);
    a1 += __shfl_xor(a1, offl);
  }
  if (lane == 0) {
    out[(size_t)b * 2 * HW + q] = a0 + bias[0];
    out[((size_t)b * 2 + 1) * HW + q] = a1 + bias[1];
  }
}

// ---------------- copy flow into mf cols 126,127 ----------------
__global__ void copy_flow_k(const float* __restrict__ flow, bf16* __restrict__ mf) {
  int g = blockIdx.x * 256 + threadIdx.x;
  int p = g % HW;
  int c = (g / HW) % 2;
  int b = g / (2 * HW);
  mf[((size_t)b * HW + p) * 128 + 126 + c] = (bf16)flow[g];
}

// ---------------- deformable sampling with inline softmax; oa=[n][96] (off|aw) ----
__global__ __launch_bounds__(256) void deform_k(const float* __restrict__ val,
                                                const float* __restrict__ oa,
                                                bf16* __restrict__ attn) {
  int g = blockIdx.x * 256 + threadIdx.x;
  int d = g & 31;
  int nh = g >> 5;
  int h = nh & 7;
  int n = nh >> 3;
  int b = n / HW;
  int p = n % HW;
  int y = p / WW, x = p % WW;
  const float* ap = oa + (size_t)n * 96 + 64 + h * 4;
  float l0 = ap[0], l1 = ap[1], l2 = ap[2], l3 = ap[3];
  float mx = fmaxf(fmaxf(l0, l1), fmaxf(l2, l3));
  float e0 = expf(l0 - mx), e1 = expf(l1 - mx), e2 = expf(l2 - mx), e3 = expf(l3 - mx);
  float inv = 1.f / (e0 + e1 + e2 + e3);
  float wts[4] = {e0 * inv, e1 * inv, e2 * inv, e3 * inv};
  const float* offp = oa + (size_t)n * 96 + h * 8;
  const float* vb = val + (size_t)b * HW * 256 + h * 32 + d;
  float acc = 0.f;
#pragma unroll
  for (int pt = 0; pt < 4; ++pt) {
    float ox = offp[pt * 2 + 0];
    float oy = offp[pt * 2 + 1];
    float w = wts[pt];
    float px = (float)x + ox, py = (float)y + oy;
    float x0f = floorf(px), y0f = floorf(py);
    int x0 = (int)x0f, y0 = (int)y0f;
    float wx = px - x0f, wy = py - y0f;
    float s = 0.f;
    if ((unsigned)x0 < WW && (unsigned)y0 < HH)
      s += vb[(size_t)(y0 * WW + x0) * 256] * (1.f - wx) * (1.f - wy);
    if ((unsigned)(x0 + 1) < WW && (unsigned)y0 < HH)
      s += vb[(size_t)(y0 * WW + x0 + 1) * 256] * wx * (1.f - wy);
    if ((unsigned)x0 < WW && (unsigned)(y0 + 1) < HH)
      s += vb[(size_t)((y0 + 1) * WW + x0) * 256] * (1.f - wx) * wy;
    if ((unsigned)(x0 + 1) < WW && (unsigned)(y0 + 1) < HH)
      s += vb[(size_t)((y0 + 1) * WW + x0 + 1) * 256] * wx * wy;
    acc += w * s;
  }
  attn[(size_t)n * 256 + h * 32 + d] = (bf16)acc;
}

// ---------------- fused residual add + LayerNorm over 256 (optional bf16 copy) ----
__global__ __launch_bounds__(256) void ln_add_k(const float* __restrict__ A,
                                                const float* __restrict__ Bv,
                                                const float* __restrict__ g,
                                                const float* __restrict__ be,
                                                float* __restrict__ out,
                                                bf16* __restrict__ outb) {
  int n = blockIdx.x;
  int c = threadIdx.x;
  float v = A[(size_t)n * 256 + c] + Bv[(size_t)n * 256 + c];
  float s1 = v, s2 = v * v;
#pragma unroll
  for (int o = 32; o > 0; o >>= 1) {
    s1 += __shfl_down(s1, o);
    s2 += __shfl_down(s2, o);
  }
  __shared__ float r1[4], r2[4], mv[2];
  int wid = c >> 6, lane = c & 63;
  if (lane == 0) {
    r1[wid] = s1;
    r2[wid] = s2;
  }
  __syncthreads();
  if (c == 0) {
    float a = r1[0] + r1[1] + r1[2] + r1[3];
    float q2 = r2[0] + r2[1] + r2[2] + r2[3];
    float mean = a * (1.f / 256.f);
    mv[0] = mean;
    mv[1] = q2 * (1.f / 256.f) - mean * mean;
  }
  __syncthreads();
  float mean = mv[0], var = mv[1];
  float r = (v - mean) * rsqrtf(var + 1e-5f) * g[c] + be[c];
  out[(size_t)n * 256 + c] = r;
  if (outb) outb[(size_t)n * 256 + c] = (bf16)r;
}

extern "C" void kernel_launch(void* const* d_in, const int* in_sizes, int n_in,
                              void* d_out, int out_size, void* d_ws, size_t ws_size,
                              hipStream_t stream) {
  const float* fmap1 = (const float*)d_in[0];
  const float* fmap2 = (const float*)d_in[1];
  const float* flow = (const float*)d_in[2];
  const float* wc1 = (const float*)d_in[3];
  const float* bc1 = (const float*)d_in[4];
  const float* wc2 = (const float*)d_in[5];
  const float* bc2 = (const float*)d_in[6];
  const float* wf1 = (const float*)d_in[7];
  const float* bf1 = (const float*)d_in[8];
  const float* wf2 = (const float*)d_in[9];
  const float* bf2 = (const float*)d_in[10];
  const float* wcf = (const float*)d_in[11];
  const float* bcf = (const float*)d_in[12];
  const float* wfh1 = (const float*)d_in[13];
  const float* bfh1 = (const float*)d_in[14];
  const float* wfh2 = (const float*)d_in[15];
  const float* bfh2 = (const float*)d_in[16];
  const float* w_off = (const float*)d_in[17];
  const float* b_off = (const float*)d_in[18];
  const float* w_aw = (const float*)d_in[19];
  const float* b_aw = (const float*)d_in[20];
  const float* w_val = (const float*)d_in[21];
  const float* b_val = (const float*)d_in[22];
  const float* w_out = (const float*)d_in[23];
  const float* b_out = (const float*)d_in[24];
  const float* ln1_g = (const float*)d_in[25];
  const float* ln1_b = (const float*)d_in[26];
  const float* w_ff1 = (const float*)d_in[27];
  const float* b_ff1 = (const float*)d_in[28];
  const float* w_ff2 = (const float*)d_in[29];
  const float* b_ff2 = (const float*)d_in[30];
  const float* ln2_g = (const float*)d_in[31];
  const float* ln2_b = (const float*)d_in[32];

  float* ws = (float*)d_ws;
  float* out_src = (float*)d_out;
  float* out_df = out_src + (size_t)BB * HW * CC;

  // ---- workspace layout (float offsets), fully de-aliased (~165 MB) ----
  const size_t F_WT = 0;
  const size_t F_CORR = 1000000;
  const size_t F_F1T = 11700000;
  const size_t F_F2T = 12900000;
  const size_t F_QB = 14100000;
  const size_t F_SRCT = 15300000;
  const size_t F_CF = 17700000;
  const size_t F_COL7 = 18200000;
  const size_t F_COR1 = 18800000;
  const size_t F_FLO1 = 20000000;
  const size_t F_CAT = 20600000;
  const size_t F_MF = 21800000;
  const size_t F_FH1 = 22400000;
  const size_t F_OA = 23600000;
  const size_t F_VAL = 24500000;
  const size_t F_ATTN = 26900000;
  const size_t F_TMP = 28100000;
  const size_t F_SRC1 = 30500000;
  const size_t F_SRC1B = 32900000;
  const size_t F_FF1 = 34100000;
  const size_t F_FF2 = 38900000;

  bf16* wkbase = (bf16*)(ws + F_WT);
  bf16* wk1 = wkbase + 0;
  bf16* wk2 = wkbase + 24576;
  bf16* wkf2 = wkbase + 466944;
  bf16* wkcf = wkbase + 540672;
  bf16* wkfh1 = wkbase + 830976;
  bf16* wl_oa = wkbase + 1125888;
  bf16* wl_val = wkbase + 1150464;
  bf16* wl_out = wkbase + 1216000;
  bf16* wl_ff1 = wkbase + 1281536;
  bf16* wl_ff2 = wkbase + 1543680;
  bf16* wk7 = wkbase + 1805824;
  bf16* corrb = (bf16*)(ws + F_CORR);
  bf16* f1t = (bf16*)(ws + F_F1T);
  bf16* f2t = (bf16*)(ws + F_F2T);
  bf16* qb = (bf16*)(ws + F_QB);
  bf16* cf = (bf16*)(ws + F_CF);
  bf16* col7 = (bf16*)(ws + F_COL7);
  bf16* cor1 = (bf16*)(ws + F_COR1);
  bf16* flo1 = (bf16*)(ws + F_FLO1);
  bf16* cat = (bf16*)(ws + F_CAT);
  bf16* mf = (bf16*)(ws + F_MF);
  bf16* fh1 = (bf16*)(ws + F_FH1);
  bf16* attnb = (bf16*)(ws + F_ATTN);
  bf16* src1b = (bf16*)(ws + F_SRC1B);
  bf16* ff1b = (bf16*)(ws + F_FF1);

  // 1. weight pack
  WtSegs segs;
  const float* srcs[12] = {wc1, wc2, wf2, wcf, wfh1, w_off, w_aw, w_val, w_out, w_ff1, w_ff2, wf1};
  unsigned offs[12] = {0, 24576, 466944, 540672, 830976, 1125888, 1142272, 1150464, 1216000, 1281536, 1543680, 1805824};
  int couts[12] = {256, 192, 64, 126, 256, 64, 32, 256, 256, 1024, 256, 128};
  int cins[12] = {81, 256, 128, 256, 128, 256, 256, 256, 256, 256, 1024, 2};
  int kps[12] = {96, 256, 128, 256, 128, 256, 256, 256, 256, 256, 1024, 128};
  int ks2[12] = {1, 9, 9, 9, 9, 1, 1, 1, 1, 1, 1, 0};
  unsigned cum = 0;
  for (int i = 0; i < 12; ++i) {
    segs.src[i] = srcs[i];
    segs.dstOff[i] = offs[i];
    segs.Cout[i] = couts[i];
    segs.Cin[i] = cins[i];
    segs.KP[i] = kps[i];
    segs.KS2[i] = ks2[i];
    segs.cum[i] = cum;
    cum += (unsigned)((ks2[i] ? ks2[i] : 1) * couts[i] * kps[i]);
  }
  segs.cum[12] = cum;
  wt_all_k<<<dim3((cum + 255) / 256), 256, 0, stream>>>(segs, wkbase);

  // 2-4. prep, im2col7, copy_flow
  prep_k<<<dim3(36, 4, 8), 256, 0, stream>>>(fmap1, fmap2, ws + F_SRCT, f1t, qb, f2t);
  im2col7_k<<<dim3(4608), 256, 0, stream>>>(flow, col7);
  copy_flow_k<<<dim3(72), 256, 0, stream>>>(flow, mf);

  // 5-6. corr + lookup
  corr_mfma_k<<<dim3(36, 18, 4), 256, 0, stream>>>(f1t, f2t, corrb);
  corr_lookup_k<<<dim3(3456), 256, 0, stream>>>(corrb, flow, cf);

  auto setseg = [](GSegs& G, int i, const bf16* in, const bf16* wt, const float* bias,
                   const float* bias2, int split, float* outf, bf16* outb, int O, int KP,
                   int taps, int OStride, int OOff, int relu) {
    G.in[i] = in; G.wt[i] = wt; G.bias[i] = bias; G.bias2[i] = bias2; G.split[i] = split;
    G.outf[i] = outf; G.outb[i] = outb; G.O[i] = O; G.KP[i] = KP; G.taps[i] = taps;
    G.OStride[i] = OStride; G.OOff[i] = OOff; G.relu[i] = relu;
    G.nTn[i] = (O + 63) / 64;
  };
  auto finseg = [](GSegs& G, int n) {
    int cumb = 0;
    for (int i = 0; i < 4; ++i) {
      if (i < n) { G.blkStart[i] = cumb; cumb += G.nTn[i] * 72; }
      else G.blkStart[i] = 0x7fffffff;
    }
    G.nseg = n;
    return cumb;
  };

  // 7. GROUP A: wc1, conv7-linear, off|aw, val
  GSegs GA;
  setseg(GA, 0, cf, wk1, bc1, nullptr, 1 << 30, nullptr, cor1, 256, 96, 1, 256, 0, 1);
  setseg(GA, 1, col7, wk7, bf1, nullptr, 1 << 30, nullptr, flo1, 128, 128, 1, 128, 0, 1);
  setseg(GA, 2, qb, wl_oa, b_off, b_aw, 64, ws + F_OA, nullptr, 96, 256, 1, 96, 0, 0);
  setseg(GA, 3, f1t, wl_val, b_val, nullptr, 1 << 30, ws + F_VAL, nullptr, 256, 256, 1, 256, 0, 0);
  int nblkA = finseg(GA, 4);
  gemm_group_k<<<dim3(nblkA), 256, 0, stream>>>(GA);

  // 8. deform
  deform_k<<<dim3(9216), 256, 0, stream>>>(ws + F_VAL, ws + F_OA, attnb);

  // 9. GROUP B: wc2, wf2, out-proj
  GSegs GB;
  setseg(GB, 0, cor1, wk2, bc2, nullptr, 1 << 30, nullptr, cat, 192, 256, 9, 256, 0, 1);
  setseg(GB, 1, flo1, wkf2, bf2, nullptr, 1 << 30, nullptr, cat, 64, 128, 9, 256, 192, 1);
  setseg(GB, 2, attnb, wl_out, b_out, nullptr, 1 << 30, ws + F_TMP, nullptr, 256, 256, 1, 256, 0, 0);
  int nblkB = finseg(GB, 3);
  gemm_group_k<<<dim3(nblkB), 256, 0, stream>>>(GB);

  // 10. LN1
  ln_add_k<<<dim3(9216), 256, 0, stream>>>(ws + F_TMP, ws + F_SRCT, ln1_g, ln1_b, ws + F_SRC1, src1b);

  // 11. GROUP C: wcf, ff1
  GSegs GC;
  setseg(GC, 0, cat, wkcf, bcf, nullptr, 1 << 30, nullptr, mf, 126, 256, 9, 128, 0, 1);
  setseg(GC, 1, src1b, wl_ff1, b_ff1, nullptr, 1 << 30, nullptr, ff1b, 1024, 256, 1, 1024, 0, 1);
  int nblkC = finseg(GC, 2);
  gemm_group_k<<<dim3(nblkC), 256, 0, stream>>>(GC);

  // 12. GROUP D: wfh1, ff2
  GSegs GD;
  setseg(GD, 0, mf, wkfh1, bfh1, nullptr, 1 << 30, nullptr, fh1, 256, 128, 9, 256, 0, 1);
  setseg(GD, 1, ff1b, wl_ff2, b_ff2, nullptr, 1 << 30, ws + F_FF2, nullptr, 256, 1024, 1, 256, 0, 0);
  int nblkD = finseg(GD, 2);
  gemm_group_k<<<dim3(nblkD), 256, 0, stream>>>(GD);

  // 13-14. flow head tail + LN2
  convfh2_k<<<dim3(2304), 256, 0, stream>>>(fh1, wfh2, bfh2, out_df);
  ln_add_k<<<dim3(9216), 256, 0, stream>>>(ws + F_FF2, ws + F_SRC1, ln2_g, ln2_b, out_src, nullptr);

  (void)in_sizes; (void)n_in; (void)out_size; (void)ws_size;
}